// Round 12
// baseline (1792.181 us; speedup 1.0000x reference)
//
#include <hip/hip_runtime.h>
#include <hip/hip_bf16.h>

// Decoder: B=32, S=128, H=256, V=32000, T=100
#define Bn 32
#define Sn 128
#define Hn 256
#define Vn 32000
#define Tn 100
#define GIn 768   // 3H
#define AGENT __HIP_MEMORY_SCOPE_AGENT

typedef __attribute__((ext_vector_type(8))) short bf16x8;
typedef __attribute__((ext_vector_type(4))) float f32x4;

__device__ __forceinline__ float frcp(float x){ return __builtin_amdgcn_rcpf(x); }
__device__ __forceinline__ float ftanh(float x){ return 1.0f - 2.0f*frcp(__expf(2.0f*x)+1.0f); }
// input pre-scaled by 2: tanh(x) given y=2x
__device__ __forceinline__ float ftanh_pre(float y){ return 1.0f - 2.0f*frcp(__expf(y)+1.0f); }
__device__ __forceinline__ float fsigm(float x){ return frcp(1.0f + __expf(-x)); }
__device__ __forceinline__ float b2f(unsigned short u){
  unsigned int v = ((unsigned int)u) << 16; return __builtin_bit_cast(float, v);
}
__device__ __forceinline__ unsigned short f2bu(float f){ // RNE f32->bf16 bits
  unsigned int u = __builtin_bit_cast(unsigned int, f);
  u += 0x7FFFu + ((u >> 16) & 1u);
  return (unsigned short)(u >> 16);
}
__device__ __forceinline__ void st_ag_u(unsigned int* p, unsigned int v){
  __hip_atomic_store(p, v, __ATOMIC_RELAXED, AGENT);
}
__device__ __forceinline__ unsigned int ld_ag_u(unsigned int* p){
  return __hip_atomic_load(p, __ATOMIC_RELAXED, AGENT);
}

// ---------------- generic 32x32 tiled transpose: out(CxR) = in(RxC)^T ----------------
__global__ __launch_bounds__(256) void k_tr(const float* __restrict__ in,
    float* __restrict__ out, int R, int C)
{
  __shared__ float tile[32][33];
  const int bx = blockIdx.x*32, by = blockIdx.y*32;
  const int tx = threadIdx.x & 31, ty = threadIdx.x >> 5;
  #pragma unroll
  for(int r = ty; r < 32; r += 8)
    if(by + r < R && bx + tx < C) tile[r][tx] = in[(size_t)(by + r)*C + bx + tx];
  __syncthreads();
  #pragma unroll
  for(int r = ty; r < 32; r += 8)
    if(bx + r < C && by + tx < R) out[(size_t)(bx + r)*R + by + tx] = tile[tx][r];
}

// ---------------- W1R: per-(half,wave) MFMA B-fragments (validated r6-r11) -------
__global__ __launch_bounds__(256) void k_packW1R(const float* __restrict__ Qw,
    const float* __restrict__ Whh, unsigned short* __restrict__ W1R)
{
  const int tid = blockIdx.x*256 + threadIdx.x;   // 0..40959
  const int lane = tid & 63;
  const int fragid = tid >> 6;                    // 0..639
  const int tt = fragid % 5;
  const int kk = (fragid/5) % 8;
  const int w  = (fragid/40) % 8;
  const int hb = fragid/320;
  const int lr = lane & 15, lg = lane >> 4;
  const float* src;
  if(tt < 2){
    const int f = w*32 + tt*16 + lr;
    src = Qw + (size_t)f*Hn;
  } else {
    const int lf = w*48 + (tt-2)*16 + lr;
    const int g = lf >> 7, jj = lf & 127;
    src = Whh + (size_t)(g*256 + hb*128 + jj)*Hn;
  }
  const int col = kk*32 + lg*8;
  float4 v0 = *(const float4*)(src + col), v1 = *(const float4*)(src + col + 4);
  unsigned short* d = W1R + ((size_t)fragid*64 + lane)*8;
  d[0]=f2bu(v0.x); d[1]=f2bu(v0.y); d[2]=f2bu(v0.z); d[3]=f2bu(v0.w);
  d[4]=f2bu(v1.x); d[5]=f2bu(v1.y); d[6]=f2bu(v1.z); d[7]=f2bu(v1.w);
}

// f32 -> bf16 (out_w)
__global__ __launch_bounds__(256) void k_cvt(const float* __restrict__ src,
    __hip_bfloat16* __restrict__ dst, int n)
{
  int i = (blockIdx.x*256 + threadIdx.x)*4;
  if(i < n){
    float4 v = *(const float4*)(src + i);
    dst[i+0] = __float2bfloat16(v.x);
    dst[i+1] = __float2bfloat16(v.y);
    dst[i+2] = __float2bfloat16(v.z);
    dst[i+3] = __float2bfloat16(v.w);
  }
}

// ---------------- enc_kb16[bs][j] = bf16( 2*(enc[bs,:]·KwT[:,j] + Kb[j]) ) -------
__global__ __launch_bounds__(256) void k_enc2(const float* __restrict__ enc_outputs,
    const float* __restrict__ KwT, const float* __restrict__ Kb,
    unsigned short* __restrict__ enc_kb16)
{
  const int r0 = blockIdx.x*16, j = threadIdx.x;
  __shared__ __align__(16) float encl[Hn][20];
  #pragma unroll
  for(int r = 0; r < 16; r++) encl[j][r] = enc_outputs[(size_t)(r0 + r)*Hn + j];
  __syncthreads();
  float acc[16];
  #pragma unroll
  for(int r = 0; r < 16; r++) acc[r] = Kb[j];
  for(int d = 0; d < Hn; d++){
    const float wv = KwT[(size_t)d*Hn + j];
    const float4 e0 = *(const float4*)&encl[d][0];
    const float4 e1 = *(const float4*)&encl[d][4];
    const float4 e2 = *(const float4*)&encl[d][8];
    const float4 e3 = *(const float4*)&encl[d][12];
    acc[0]+=e0.x*wv; acc[1]+=e0.y*wv; acc[2]+=e0.z*wv; acc[3]+=e0.w*wv;
    acc[4]+=e1.x*wv; acc[5]+=e1.y*wv; acc[6]+=e1.z*wv; acc[7]+=e1.w*wv;
    acc[8]+=e2.x*wv; acc[9]+=e2.y*wv; acc[10]+=e2.z*wv; acc[11]+=e2.w*wv;
    acc[12]+=e3.x*wv; acc[13]+=e3.y*wv; acc[14]+=e3.z*wv; acc[15]+=e3.w*wv;
  }
  #pragma unroll
  for(int r = 0; r < 16; r++) enc_kb16[(size_t)(r0 + r)*Hn + j] = f2bu(2.0f*acc[r]);
}

// ---------------- ekP: enc_k permuted to phase-2 consumption order (validated) ----
__global__ __launch_bounds__(256) void k_packEk(const unsigned short* __restrict__ enc_kb16,
    unsigned short* __restrict__ ekP)
{
  const int tid = blockIdx.x*256 + threadIdx.x;   // 0..131071
  const int b = tid >> 12;
  const int o = tid & 4095;
  const int g = o >> 6, l = o & 63;
  const int w = g >> 3, i = g & 7;
  const int s = w*16 + (l >> 2);
  const int e0 = i*32 + (l & 3)*8;
  const int4 v = *(const int4*)(enc_kb16 + ((size_t)(b*Sn + s))*Hn + e0);
  *(int4*)(ekP + (size_t)b*32768 + (size_t)o*8) = v;
}

// ---------------- encW2F: MFMA B-fragment layout per (b, hb) (validated) ---------
__global__ __launch_bounds__(768) void k_encW2F(const float* __restrict__ enc_outputs,
    const float* __restrict__ W_ihT, unsigned short* __restrict__ encW2F)
{
  const int r0 = blockIdx.x*16, tid = threadIdx.x;   // tid = j
  __shared__ __align__(16) float encl[Hn][20];
  if(tid < Hn){
    #pragma unroll
    for(int r = 0; r < 16; r++) encl[tid][r] = enc_outputs[(size_t)(r0 + r)*Hn + tid];
  }
  __syncthreads();
  float acc[16];
  #pragma unroll
  for(int r = 0; r < 16; r++) acc[r] = 0.f;
  for(int d = 0; d < Hn; d++){
    const float wv = W_ihT[(size_t)(Hn + d)*GIn + tid];
    const float4 e0 = *(const float4*)&encl[d][0];
    const float4 e1 = *(const float4*)&encl[d][4];
    const float4 e2 = *(const float4*)&encl[d][8];
    const float4 e3 = *(const float4*)&encl[d][12];
    acc[0]+=e0.x*wv; acc[1]+=e0.y*wv; acc[2]+=e0.z*wv; acc[3]+=e0.w*wv;
    acc[4]+=e1.x*wv; acc[5]+=e1.y*wv; acc[6]+=e1.z*wv; acc[7]+=e1.w*wv;
    acc[8]+=e2.x*wv; acc[9]+=e2.y*wv; acc[10]+=e2.z*wv; acc[11]+=e2.w*wv;
    acc[12]+=e3.x*wv; acc[13]+=e3.y*wv; acc[14]+=e3.z*wv; acc[15]+=e3.w*wv;
  }
  const int g = tid >> 8, jj = tid & 255;
  const int hb = jj >> 7, jl = jj & 127;
  const int c = g*128 + jl;
  const int wvv = c/48, rem = c - wvv*48, tt = rem >> 4, lr = rem & 15;
  #pragma unroll
  for(int r = 0; r < 16; r++){
    const int bs = r0 + r;
    const int bb = bs >> 7, s = bs & 127;
    const int kk = s >> 5, lg = (s >> 3) & 3, e = s & 7;
    const int lane = lg*16 + lr;
    encW2F[(size_t)(bb*2 + hb)*49152 + (size_t)((wvv*12 + tt*4 + kk)*64 + lane)*8 + e]
        = f2bu(acc[r]);
  }
}

// ---------------- gi_emb[t*32+b][j] = emb(tok)·W_ihT[:256, j] + b_ih[j]  (f32) ----------------
__global__ __launch_bounds__(768) void k_giemb2(const int* __restrict__ target,
    const float* __restrict__ embedding, const float* __restrict__ W_ihT,
    const float* __restrict__ b_ih, float* __restrict__ gi_emb)
{
  const int r0 = blockIdx.x*16, tid = threadIdx.x;
  __shared__ __align__(16) float embl[Hn][20];
  if(tid < Hn){
    #pragma unroll
    for(int r = 0; r < 16; r++){
      const int row = r0 + r;            // t*32+b
      const int t = row >> 5, b = row & 31;
      const int tok = (t == 0) ? 0 : target[b*Tn + (t-1)];
      embl[tid][r] = embedding[(size_t)tok*Hn + tid];
    }
  }
  __syncthreads();
  float acc[16];
  #pragma unroll
  for(int r = 0; r < 16; r++) acc[r] = b_ih[tid];
  for(int d = 0; d < Hn; d++){
    const float wv = W_ihT[(size_t)d*GIn + tid];
    const float4 e0 = *(const float4*)&embl[d][0];
    const float4 e1 = *(const float4*)&embl[d][4];
    const float4 e2 = *(const float4*)&embl[d][8];
    const float4 e3 = *(const float4*)&embl[d][12];
    acc[0]+=e0.x*wv; acc[1]+=e0.y*wv; acc[2]+=e0.z*wv; acc[3]+=e0.w*wv;
    acc[4]+=e1.x*wv; acc[5]+=e1.y*wv; acc[6]+=e1.z*wv; acc[7]+=e1.w*wv;
    acc[8]+=e2.x*wv; acc[9]+=e2.y*wv; acc[10]+=e2.z*wv; acc[11]+=e2.w*wv;
    acc[12]+=e3.x*wv; acc[13]+=e3.y*wv; acc[14]+=e3.z*wv; acc[15]+=e3.w*wv;
  }
  #pragma unroll
  for(int r = 0; r < 16; r++) gi_emb[(size_t)(r0 + r)*GIn + tid] = acc[r];
}

// ---------------- serial recurrence: r11's k_loop7 + 1A/1B poll-overlap ----------
// Phase 1 split: own-half-K MFMAs first (h own slice, ready at prior b5), wave-0
// pulls partner h DURING 1A, barrier, then partner-half-K. Flag: end of step t
// releases t+1; step t (t>=1) polls >= t. No pre-push (h(0) from enc_hidden).
__global__ __launch_bounds__(512, 2) void k_loop9(
    const float* __restrict__ enc_hidden,
    const unsigned short* __restrict__ ekP,        // (B,32768) packed (2x-scaled)
    const unsigned short* __restrict__ encW2F,     // (B,2,49152) frag-packed
    const unsigned short* __restrict__ W1R,        // (2,8,40,64,8)
    const float* __restrict__ Qb, const float* __restrict__ b_hh,
    const float* __restrict__ Vw, const float* __restrict__ Vb,
    const float* __restrict__ gi_emb,              // (T*B,3H) f32
    __hip_bfloat16* __restrict__ h_all,
    float* __restrict__ atts_out,
    float* __restrict__ hfin_out,
    unsigned int* hbuf,            // [2][32][2][64]
    unsigned int* hflag)           // [32][2]
{
  const int bid = blockIdx.x;
  const int hb = (bid >> 3) & 1;
  const int p  = (bid & 7) | ((bid >> 4) << 3);
  const int b = p;
  const int tid = threadIdx.x;
  const int lane = tid & 63, wv = tid >> 6;        // 8 waves
  const int lr = lane & 15, lg = lane >> 4;

  __shared__ __align__(16) unsigned short ew_l[49152];    // 96 KB encW2 frags
  __shared__ __align__(16) float h_sh[128];               // own h slice f32
  __shared__ __align__(16) short h_b16[Hn];               // full h bf16
  __shared__ __align__(16) float qgh_sh[1024];
  __shared__ __align__(16) float vw_sh[Hn];
  __shared__ __align__(16) float sc_sh[Sn];
  __shared__ __align__(16) unsigned short wb_l[Sn];
  __shared__ __align__(16) float gic_l[384];

  // ---- one-time staging ----
  {
    const unsigned short* src = encW2F + (size_t)(b*2 + hb)*49152;
    #pragma unroll
    for(int c = 0; c < 12; c++){
      const int idx = (c*512 + tid)*8;
      *(int4*)(ew_l + idx) = *(const int4*)(src + idx);
    }
  }
  bf16x8 ekr[8];
  {
    const unsigned short* esrc = ekP + (size_t)b*32768;
    #pragma unroll
    for(int i = 0; i < 8; i++)
      ekr[i] = *(const bf16x8*)(esrc + (size_t)((wv*8 + i)*64 + lane)*8);
  }
  bf16x8 w1f[40];
  {
    const unsigned short* wsrc = W1R + (((size_t)(hb*8 + wv)*40)*64 + lane)*8;
    #pragma unroll
    for(int f = 0; f < 40; f++) w1f[f] = *(const bf16x8*)(wsrc + (size_t)f*512);
  }
  float bias_r[5]; int idx_r[5];
  #pragma unroll
  for(int tt = 0; tt < 2; tt++){
    const int f = wv*32 + tt*16 + lr;
    bias_r[tt] = Qb[f]; idx_r[tt] = f;
  }
  #pragma unroll
  for(int tt = 2; tt < 5; tt++){
    const int lf = wv*48 + (tt-2)*16 + lr;
    const int g = lf >> 7, jj = lf & 127;
    bias_r[tt] = b_hh[g*256 + hb*128 + jj];
    idx_r[tt]  = 256 + g*256 + hb*128 + jj;
  }
  if(tid < Hn){
    vw_sh[tid] = Vw[tid];
    h_b16[tid] = (short)f2bu(enc_hidden[b*Hn + tid]);
  }
  if(tid < 128) h_sh[tid] = enc_hidden[b*Hn + hb*128 + tid];
  __syncthreads();
  const float vb0 = Vb[0];
  const int g2 = tid & 3;

  for(int t = 0; t < Tn; t++){
    f32x4 acc[5];
    #pragma unroll
    for(int tt = 0; tt < 5; tt++) acc[tt] = (f32x4){0.f,0.f,0.f,0.f};
    // ---- phase 1A: own-half-K MFMAs (h_b16 own half is current) ----
    #pragma unroll
    for(int kkl = 0; kkl < 4; kkl++){
      const int kch = hb*4 + kkl;
      bf16x8 a = *(const bf16x8*)(h_b16 + kch*32 + lg*8);
      #pragma unroll
      for(int tt = 0; tt < 5; tt++)
        acc[tt] = __builtin_amdgcn_mfma_f32_16x16x32_bf16(a, w1f[kch*5 + tt], acc[tt], 0, 0, 0);
    }
    // ---- wave-0: pull partner h(t) (overlaps 1A of other waves / RTT) ----
    if(t > 0 && tid < 64){
      long cnt = 0;
      while(__hip_atomic_load(&hflag[p*2 + (hb^1)], __ATOMIC_ACQUIRE, AGENT) < (unsigned)t
            && ++cnt < 10000000L){}
      unsigned int u = ld_ag_u(&hbuf[((size_t)((t & 1)*32 + p)*2 + (hb^1))*64 + tid]);
      ((unsigned int*)h_b16)[(hb^1)*64 + tid] = u;
    }
    __syncthreads();                                   // bA: partner h in LDS
    // ---- phase 1B: partner-half-K MFMAs ----
    #pragma unroll
    for(int kkl = 0; kkl < 4; kkl++){
      const int kch = (1 - hb)*4 + kkl;
      bf16x8 a = *(const bf16x8*)(h_b16 + kch*32 + lg*8);
      #pragma unroll
      for(int tt = 0; tt < 5; tt++)
        acc[tt] = __builtin_amdgcn_mfma_f32_16x16x32_bf16(a, w1f[kch*5 + tt], acc[tt], 0, 0, 0);
    }
    if(lane < 16){
      #pragma unroll
      for(int tt = 0; tt < 5; tt++){
        float v = acc[tt][0] + bias_r[tt];
        if(tt < 2) v *= 2.0f;          // pre-scale q by 2 for phase-2 tanh
        qgh_sh[idx_r[tt]] = v;
      }
    }
    __syncthreads();                                   // b1: qgh ready

    // ---- phase 2: all 128 scores (redundant), enc_k from registers ----
    {
      float pacc = 0.f;
      #pragma unroll
      for(int i = 0; i < 8; i++){
        const bf16x8 e8 = ekr[i];
        const int kb = i*32 + g2*8;
        #pragma unroll
        for(int j = 0; j < 8; j++){
          float ev = b2f((unsigned short)e8[j]);
          pacc = fmaf(vw_sh[kb + j], ftanh_pre(qgh_sh[kb + j] + ev), pacc);
        }
      }
      pacc += __shfl_xor(pacc, 1); pacc += __shfl_xor(pacc, 2);
      if(g2 == 0) sc_sh[tid >> 2] = pacc + vb0;
    }
    __syncthreads();                                   // b2: scores ready

    // ---- softmax over S=128 (wave 0, redundant both halves) ----
    if(tid < 64){
      float v0 = sc_sh[tid], v1 = sc_sh[tid + 64];
      float m = fmaxf(v0, v1);
      #pragma unroll
      for(int off = 1; off < 64; off <<= 1) m = fmaxf(m, __shfl_xor(m, off));
      float e0 = __expf(v0 - m), e1 = __expf(v1 - m);
      float sm = e0 + e1;
      #pragma unroll
      for(int off = 1; off < 64; off <<= 1) sm += __shfl_xor(sm, off);
      float inv = frcp(sm);
      float w0 = e0*inv, w1 = e1*inv;
      wb_l[tid] = f2bu(w0); wb_l[tid + 64] = f2bu(w1);
      if(hb == 0){
        float* ao = atts_out + ((size_t)b*Tn + t)*Sn;
        ao[tid] = w0; ao[tid + 64] = w1;
      }
    }
    float ge0 = 0.f, ge1 = 0.f, ge2 = 0.f;
    if(tid < 128){
      const float* ge = gi_emb + ((size_t)t*Bn + b)*GIn + hb*128 + tid;
      ge0 = ge[0]; ge1 = ge[256]; ge2 = ge[512];
    }
    __syncthreads();                                   // b3: w ready

    // ---- phase 3: own gi_ctx (384 cols) = w @ encW2 via MFMA ----
    {
      bf16x8 wfrag[4];
      #pragma unroll
      for(int kk = 0; kk < 4; kk++)
        wfrag[kk] = *(const bf16x8*)(wb_l + kk*32 + lg*8);
      #pragma unroll
      for(int tt = 0; tt < 3; tt++){
        f32x4 a3 = (f32x4){0.f,0.f,0.f,0.f};
        #pragma unroll
        for(int kk = 0; kk < 4; kk++){
          bf16x8 bfr = *(const bf16x8*)(ew_l + (size_t)((wv*12 + tt*4 + kk)*64 + lane)*8);
          a3 = __builtin_amdgcn_mfma_f32_16x16x32_bf16(wfrag[kk], bfr, a3, 0, 0, 0);
        }
        if(lane < 16) gic_l[wv*48 + tt*16 + lane] = a3[0];
      }
    }
    __syncthreads();                                   // b4: gic ready

    // ---- phase 4: GRU own j-slice + push h(t+1) slice ----
    if(tid < 128){
      float gr = ge0 + gic_l[tid];
      float gz = ge1 + gic_l[128 + tid];
      float gn = ge2 + gic_l[256 + tid];
      const int jg = hb*128 + tid;
      float r = fsigm(gr + qgh_sh[256 + jg]);
      float z = fsigm(gz + qgh_sh[512 + jg]);
      float n = ftanh(gn + r*qgh_sh[768 + jg]);
      float hn2 = (1.0f - z)*n + z*h_sh[tid];
      h_sh[tid] = hn2;
      const unsigned short hb16 = f2bu(hn2);
      h_b16[jg] = (short)hb16;
      h_all[((size_t)t*Bn + b)*Hn + jg] = __float2bfloat16(hn2);
      if(t == Tn-1) hfin_out[b*Hn + jg] = hn2;
      if(t < Tn-1){
        float hnx = __shfl_down(hn2, 1);
        if(!(tid & 1)){
          unsigned int u = (unsigned int)hb16 | ((unsigned int)f2bu(hnx) << 16);
          st_ag_u(&hbuf[((size_t)(((t+1) & 1)*32 + p)*2 + hb)*64 + (tid >> 1)], u);
        }
      }
    }
    __syncthreads();                                   // b5: drain pushes + h_b16 own
    if(tid == 0 && t < Tn-1)
      __hip_atomic_store(&hflag[p*2 + hb], (unsigned)(t + 1), __ATOMIC_RELEASE, AGENT);
  }
}

// ---------------- logits GEMM: 128x128 tile, A in regs, B single-stage LDS -------
// ONE barrier: A-tile -> 32 bf16x8/lane (each instr covers full 64B lines, A is
// L2-resident); B-tile (64KB) -> XOR-swizzled LDS (c8^(r&7), 2-way-free reads).
__global__ __launch_bounds__(256, 2) void k_lg4(
    const unsigned short* __restrict__ h_all, const unsigned short* __restrict__ w_bf,
    const float* __restrict__ out_b,
    float* __restrict__ pmax, float* __restrict__ psum,
    const float* __restrict__ lse, float* __restrict__ dec_out,
    int pass)
{
  const int tid = threadIdx.x;
  const int lane = tid & 63, w = tid >> 6;
  const int lr = lane & 15, lg = lane >> 4;
  const int wm = w >> 1, wn = w & 1;              // 2x2 waves of 64x64
  const int m0 = blockIdx.x*128;                  // 25 blocks  (3200/128)
  const int n0 = blockIdx.y*128;                  // 250 blocks (32000/128)
  const int nchunk = blockIdx.y;
  __shared__ __align__(16) unsigned short Bs[128*256];   // 64KB swizzled

  // A -> registers (issued first; drains under B staging)
  bf16x8 am[4][8];
  {
    const unsigned short* abase = h_all + (size_t)(m0 + wm*64 + lr)*Hn + lg*8;
    #pragma unroll
    for(int mt = 0; mt < 4; mt++)
      #pragma unroll
      for(int kk = 0; kk < 8; kk++)
        am[mt][kk] = *(const bf16x8*)(abase + (size_t)(mt*16)*Hn + kk*32);
  }
  // B -> LDS, swizzled: Bs[r*256 + ((c8^(r&7))<<3)] = B[n0+r][c8*8..+8]
  {
    #pragma unroll
    for(int it = 0; it < 16; it++){
      const int id = it*256 + tid;
      const int r = id >> 5, c8 = id & 31;
      const int4 v = *(const int4*)(w_bf + (size_t)(n0 + r)*Hn + c8*8);
      *(int4*)(Bs + r*256 + ((c8 ^ (r & 7)) << 3)) = v;
    }
  }
  __syncthreads();

  f32x4 acc[4][4];
  #pragma unroll
  for(int mt = 0; mt < 4; mt++)
    #pragma unroll
    for(int nt = 0; nt < 4; nt++) acc[mt][nt] = (f32x4){0.f,0.f,0.f,0.f};

  #pragma unroll
  for(int kk = 0; kk < 8; kk++){
    bf16x8 bn[4];
    #pragma unroll
    for(int nt = 0; nt < 4; nt++){
      const int row = wn*64 + nt*16 + lr;
      const int c8 = kk*4 + lg;
      bn[nt] = *(const bf16x8*)(Bs + row*256 + ((c8 ^ (row & 7)) << 3));
    }
    #pragma unroll
    for(int mt = 0; mt < 4; mt++)
      #pragma unroll
      for(int nt = 0; nt < 4; nt++)
        acc[mt][nt] = __builtin_amdgcn_mfma_f32_16x16x32_bf16(am[mt][kk], bn[nt], acc[mt][nt], 0, 0, 0);
  }

  float bias[4];
  #pragma unroll
  for(int nt = 0; nt < 4; nt++) bias[nt] = out_b[n0 + wn*64 + nt*16 + lr];

  if(pass == 0){
    __shared__ float pm_l[128][2];
    __shared__ float ps_l[128][2];
    #pragma unroll
    for(int mt = 0; mt < 4; mt++){
      #pragma unroll
      for(int i = 0; i < 4; i++){
        float v0 = acc[mt][0][i] + bias[0], v1 = acc[mt][1][i] + bias[1];
        float v2 = acc[mt][2][i] + bias[2], v3 = acc[mt][3][i] + bias[3];
        float m = fmaxf(fmaxf(v0, v1), fmaxf(v2, v3));
        m = fmaxf(m, __shfl_xor(m, 1)); m = fmaxf(m, __shfl_xor(m, 2));
        m = fmaxf(m, __shfl_xor(m, 4)); m = fmaxf(m, __shfl_xor(m, 8));
        float s = __expf(v0 - m) + __expf(v1 - m) + __expf(v2 - m) + __expf(v3 - m);
        s += __shfl_xor(s, 1); s += __shfl_xor(s, 2);
        s += __shfl_xor(s, 4); s += __shfl_xor(s, 8);
        if(lr == 0){
          const int rl = wm*64 + mt*16 + lg*4 + i;
          pm_l[rl][wn] = m; ps_l[rl][wn] = s;
        }
      }
    }
    __syncthreads();
    if(tid < 128){
      float m = fmaxf(pm_l[tid][0], pm_l[tid][1]);
      float s = ps_l[tid][0]*__expf(pm_l[tid][0] - m) + ps_l[tid][1]*__expf(pm_l[tid][1] - m);
      pmax[(size_t)nchunk*3200 + m0 + tid] = m;
      psum[(size_t)nchunk*3200 + m0 + tid] = s;
    }
  } else {
    #pragma unroll
    for(int mt = 0; mt < 4; mt++){
      #pragma unroll
      for(int i = 0; i < 4; i++){
        const int rg = m0 + wm*64 + mt*16 + lg*4 + i;
        const float l = lse[rg];
        const int bb = rg & 31, tt2 = rg >> 5;
        float* dst = dec_out + (size_t)bb*((size_t)Tn*Vn) + (size_t)tt2*Vn + n0 + wn*64;
        dst[ 0 + lr] = acc[mt][0][i] + bias[0] - l;
        dst[16 + lr] = acc[mt][1][i] + bias[1] - l;
        dst[32 + lr] = acc[mt][2][i] + bias[2] - l;
        dst[48 + lr] = acc[mt][3][i] + bias[3] - l;
      }
    }
  }
}

// ---------------- lse combine: 4 threads/row, shuffle-combine ----------------
__global__ __launch_bounds__(256) void k_lse2(const float* __restrict__ pmax,
    const float* __restrict__ psum, float* __restrict__ lse)
{
  const int row = blockIdx.x*64 + (threadIdx.x >> 2);   // 50 blocks x 64 rows
  const int q = threadIdx.x & 3;
  float m = -3.0e38f;
  for(int c = q; c < 250; c += 4) m = fmaxf(m, pmax[(size_t)c*3200 + row]);
  float mg = m;
  mg = fmaxf(mg, __shfl_xor(mg, 1));
  mg = fmaxf(mg, __shfl_xor(mg, 2));
  float s = 0.f;
  for(int c = q; c < 250; c += 4)
    s += psum[(size_t)c*3200 + row] * __expf(pmax[(size_t)c*3200 + row] - mg);
  s += __shfl_xor(s, 1);
  s += __shfl_xor(s, 2);
  if(q == 0) lse[row] = mg + __logf(s);
}

// ---------------- launch ----------------
extern "C" void kernel_launch(void* const* d_in, const int* in_sizes, int n_in,
                              void* d_out, int out_size, void* d_ws, size_t ws_size,
                              hipStream_t stream)
{
  const float* enc_outputs = (const float*)d_in[0];
  const float* enc_hidden  = (const float*)d_in[1];
  const int*   target      = (const int*)d_in[2];
  const float* embedding   = (const float*)d_in[3];
  const float* Qw   = (const float*)d_in[4];
  const float* Qb   = (const float*)d_in[5];
  const float* Kw   = (const float*)d_in[6];
  const float* Kb   = (const float*)d_in[7];
  const float* Vw   = (const float*)d_in[8];
  const float* Vb   = (const float*)d_in[9];
  const float* W_ih = (const float*)d_in[10];
  const float* W_hh = (const float*)d_in[11];
  const float* b_ih = (const float*)d_in[12];
  const float* b_hh = (const float*)d_in[13];
  const float* out_w = (const float*)d_in[14];
  const float* out_b = (const float*)d_in[15];

  float* dec  = (float*)d_out;                       // (B,T,V)
  float* hfin = dec + (size_t)Bn*Tn*Vn;              // (1,B,H)
  float* atts = hfin + Bn*Hn;                        // (B,T,S)

  // Scratch inside dec region (fully consumed before pass-1 overwrites):
  unsigned short* enc_kb16 = (unsigned short*)(dec);            // 524,288 f32 slots
  unsigned short* ekP      = (unsigned short*)(dec + 524288);   // 524,288
  unsigned short* encW2F   = (unsigned short*)(dec + 1048576);  // 1,572,864
  float* gi_emb = dec + 2621440;                                // 2,457,600
  float* W_ihT  = dec + 5079040;                                // 393,216
  float* KwT    = dec + 5472256;                                // 65,536
  float* pmax   = dec + 5537792;                                // 800,000 (250x3200)
  float* psum   = dec + 6337792;                                // 800,000
  unsigned short* W1R = (unsigned short*)(dec + 7137792);       // 163,840 f32 slots
  unsigned int* hbuf  = (unsigned int*)(dec + 7301632);         // 8,192
  unsigned int* hflag = (unsigned int*)(dec + 7309824);         // 64 (ends 7,309,888)

  // ws: lse + h_all(bf16) + out_w(bf16)
  float* wsf = (float*)d_ws;
  float* lse = wsf;
  __hip_bfloat16* h_all = (__hip_bfloat16*)(wsf + 3200);
  __hip_bfloat16* w_bf  = h_all + (size_t)Tn*Bn*Hn;

  // prep
  k_tr     <<<dim3(8, 8),   dim3(256), 0, stream>>>(Kw, KwT, 256, 256);
  k_tr     <<<dim3(16, 24), dim3(256), 0, stream>>>(W_ih, W_ihT, 768, 512);
  k_packW1R<<<dim3(160),    dim3(256), 0, stream>>>(Qw, W_hh, W1R);
  k_cvt    <<<dim3((Vn*Hn)/1024), dim3(256), 0, stream>>>(out_w, w_bf, Vn*Hn);
  k_enc2   <<<dim3(256), dim3(256), 0, stream>>>(enc_outputs, KwT, Kb, enc_kb16);
  k_packEk <<<dim3(512), dim3(256), 0, stream>>>(enc_kb16, ekP);
  k_encW2F <<<dim3(256), dim3(768), 0, stream>>>(enc_outputs, W_ihT, encW2F);
  k_giemb2 <<<dim3(200), dim3(768), 0, stream>>>(target, embedding, W_ihT, b_ih, gi_emb);

  // reset flags (stream-ordered before k_loop9)
  hipMemsetAsync((void*)hflag, 0, 64*sizeof(unsigned int), stream);

  // recurrence: 64 co-resident blocks, one exchange/step, poll overlapped with 1A
  k_loop9 <<<dim3(64), dim3(512), 0, stream>>>(enc_hidden, ekP, encW2F, W1R,
            Qb, b_hh, Vw, Vb, gi_emb, h_all, atts, hfin, hbuf, hflag);

  // logits + log_softmax (single-stage GEMM)
  k_lg4   <<<dim3(25, 250), dim3(256), 0, stream>>>(
            (const unsigned short*)h_all, (const unsigned short*)w_bf, out_b,
            pmax, psum, (const float*)nullptr, (float*)nullptr, 0);
  k_lse2  <<<dim3(50), dim3(256), 0, stream>>>(pmax, psum, lse);
  k_lg4   <<<dim3(25, 250), dim3(256), 0, stream>>>(
            (const unsigned short*)h_all, (const unsigned short*)w_bf, out_b,
            (float*)nullptr, (float*)nullptr, lse, dec, 1);
}

// Round 13
// 1181.151 us; speedup vs baseline: 1.5173x; 1.5173x over previous
//
#include <hip/hip_runtime.h>
#include <hip/hip_bf16.h>

// Decoder: B=32, S=128, H=256, V=32000, T=100
#define Bn 32
#define Sn 128
#define Hn 256
#define Vn 32000
#define Tn 100
#define GIn 768   // 3H
#define AGENT __HIP_MEMORY_SCOPE_AGENT

typedef __attribute__((ext_vector_type(8))) short bf16x8;
typedef __attribute__((ext_vector_type(4))) float f32x4;

__device__ __forceinline__ float frcp(float x){ return __builtin_amdgcn_rcpf(x); }
__device__ __forceinline__ float ftanh(float x){ return 1.0f - 2.0f*frcp(__expf(2.0f*x)+1.0f); }
// input pre-scaled by 2: tanh(x) given y=2x
__device__ __forceinline__ float ftanh_pre(float y){ return 1.0f - 2.0f*frcp(__expf(y)+1.0f); }
__device__ __forceinline__ float fsigm(float x){ return frcp(1.0f + __expf(-x)); }
__device__ __forceinline__ float b2f(unsigned short u){
  unsigned int v = ((unsigned int)u) << 16; return __builtin_bit_cast(float, v);
}
__device__ __forceinline__ unsigned short f2bu(float f){ // RNE f32->bf16 bits
  unsigned int u = __builtin_bit_cast(unsigned int, f);
  u += 0x7FFFu + ((u >> 16) & 1u);
  return (unsigned short)(u >> 16);
}
__device__ __forceinline__ void st_ag_u(unsigned int* p, unsigned int v){
  __hip_atomic_store(p, v, __ATOMIC_RELAXED, AGENT);
}
__device__ __forceinline__ unsigned int ld_ag_u(unsigned int* p){
  return __hip_atomic_load(p, __ATOMIC_RELAXED, AGENT);
}

// ---------------- generic 32x32 tiled transpose: out(CxR) = in(RxC)^T ----------------
__global__ __launch_bounds__(256) void k_tr(const float* __restrict__ in,
    float* __restrict__ out, int R, int C)
{
  __shared__ float tile[32][33];
  const int bx = blockIdx.x*32, by = blockIdx.y*32;
  const int tx = threadIdx.x & 31, ty = threadIdx.x >> 5;
  #pragma unroll
  for(int r = ty; r < 32; r += 8)
    if(by + r < R && bx + tx < C) tile[r][tx] = in[(size_t)(by + r)*C + bx + tx];
  __syncthreads();
  #pragma unroll
  for(int r = ty; r < 32; r += 8)
    if(bx + r < C && by + tx < R) out[(size_t)(bx + r)*R + by + tx] = tile[tx][r];
}

// ---------------- W1R: per-(half,wave) MFMA B-fragments (validated r6-r11) -------
__global__ __launch_bounds__(256) void k_packW1R(const float* __restrict__ Qw,
    const float* __restrict__ Whh, unsigned short* __restrict__ W1R)
{
  const int tid = blockIdx.x*256 + threadIdx.x;   // 0..40959
  const int lane = tid & 63;
  const int fragid = tid >> 6;                    // 0..639
  const int tt = fragid % 5;
  const int kk = (fragid/5) % 8;
  const int w  = (fragid/40) % 8;
  const int hb = fragid/320;
  const int lr = lane & 15, lg = lane >> 4;
  const float* src;
  if(tt < 2){
    const int f = w*32 + tt*16 + lr;
    src = Qw + (size_t)f*Hn;
  } else {
    const int lf = w*48 + (tt-2)*16 + lr;
    const int g = lf >> 7, jj = lf & 127;
    src = Whh + (size_t)(g*256 + hb*128 + jj)*Hn;
  }
  const int col = kk*32 + lg*8;
  float4 v0 = *(const float4*)(src + col), v1 = *(const float4*)(src + col + 4);
  unsigned short* d = W1R + ((size_t)fragid*64 + lane)*8;
  d[0]=f2bu(v0.x); d[1]=f2bu(v0.y); d[2]=f2bu(v0.z); d[3]=f2bu(v0.w);
  d[4]=f2bu(v1.x); d[5]=f2bu(v1.y); d[6]=f2bu(v1.z); d[7]=f2bu(v1.w);
}

// f32 -> bf16 (out_w)
__global__ __launch_bounds__(256) void k_cvt(const float* __restrict__ src,
    __hip_bfloat16* __restrict__ dst, int n)
{
  int i = (blockIdx.x*256 + threadIdx.x)*4;
  if(i < n){
    float4 v = *(const float4*)(src + i);
    dst[i+0] = __float2bfloat16(v.x);
    dst[i+1] = __float2bfloat16(v.y);
    dst[i+2] = __float2bfloat16(v.z);
    dst[i+3] = __float2bfloat16(v.w);
  }
}

// ---------------- enc_kb16[bs][j] = bf16( 2*(enc[bs,:]·KwT[:,j] + Kb[j]) ) -------
__global__ __launch_bounds__(256) void k_enc2(const float* __restrict__ enc_outputs,
    const float* __restrict__ KwT, const float* __restrict__ Kb,
    unsigned short* __restrict__ enc_kb16)
{
  const int r0 = blockIdx.x*16, j = threadIdx.x;
  __shared__ __align__(16) float encl[Hn][20];
  #pragma unroll
  for(int r = 0; r < 16; r++) encl[j][r] = enc_outputs[(size_t)(r0 + r)*Hn + j];
  __syncthreads();
  float acc[16];
  #pragma unroll
  for(int r = 0; r < 16; r++) acc[r] = Kb[j];
  for(int d = 0; d < Hn; d++){
    const float wv = KwT[(size_t)d*Hn + j];
    const float4 e0 = *(const float4*)&encl[d][0];
    const float4 e1 = *(const float4*)&encl[d][4];
    const float4 e2 = *(const float4*)&encl[d][8];
    const float4 e3 = *(const float4*)&encl[d][12];
    acc[0]+=e0.x*wv; acc[1]+=e0.y*wv; acc[2]+=e0.z*wv; acc[3]+=e0.w*wv;
    acc[4]+=e1.x*wv; acc[5]+=e1.y*wv; acc[6]+=e1.z*wv; acc[7]+=e1.w*wv;
    acc[8]+=e2.x*wv; acc[9]+=e2.y*wv; acc[10]+=e2.z*wv; acc[11]+=e2.w*wv;
    acc[12]+=e3.x*wv; acc[13]+=e3.y*wv; acc[14]+=e3.z*wv; acc[15]+=e3.w*wv;
  }
  #pragma unroll
  for(int r = 0; r < 16; r++) enc_kb16[(size_t)(r0 + r)*Hn + j] = f2bu(2.0f*acc[r]);
}

// ---------------- ekP: enc_k permuted to phase-2 consumption order (validated) ----
__global__ __launch_bounds__(256) void k_packEk(const unsigned short* __restrict__ enc_kb16,
    unsigned short* __restrict__ ekP)
{
  const int tid = blockIdx.x*256 + threadIdx.x;   // 0..131071
  const int b = tid >> 12;
  const int o = tid & 4095;
  const int g = o >> 6, l = o & 63;
  const int w = g >> 3, i = g & 7;
  const int s = w*16 + (l >> 2);
  const int e0 = i*32 + (l & 3)*8;
  const int4 v = *(const int4*)(enc_kb16 + ((size_t)(b*Sn + s))*Hn + e0);
  *(int4*)(ekP + (size_t)b*32768 + (size_t)o*8) = v;
}

// ---------------- encW2F: MFMA B-fragment layout per (b, hb) (validated) ---------
__global__ __launch_bounds__(768) void k_encW2F(const float* __restrict__ enc_outputs,
    const float* __restrict__ W_ihT, unsigned short* __restrict__ encW2F)
{
  const int r0 = blockIdx.x*16, tid = threadIdx.x;   // tid = j
  __shared__ __align__(16) float encl[Hn][20];
  if(tid < Hn){
    #pragma unroll
    for(int r = 0; r < 16; r++) encl[tid][r] = enc_outputs[(size_t)(r0 + r)*Hn + tid];
  }
  __syncthreads();
  float acc[16];
  #pragma unroll
  for(int r = 0; r < 16; r++) acc[r] = 0.f;
  for(int d = 0; d < Hn; d++){
    const float wv = W_ihT[(size_t)(Hn + d)*GIn + tid];
    const float4 e0 = *(const float4*)&encl[d][0];
    const float4 e1 = *(const float4*)&encl[d][4];
    const float4 e2 = *(const float4*)&encl[d][8];
    const float4 e3 = *(const float4*)&encl[d][12];
    acc[0]+=e0.x*wv; acc[1]+=e0.y*wv; acc[2]+=e0.z*wv; acc[3]+=e0.w*wv;
    acc[4]+=e1.x*wv; acc[5]+=e1.y*wv; acc[6]+=e1.z*wv; acc[7]+=e1.w*wv;
    acc[8]+=e2.x*wv; acc[9]+=e2.y*wv; acc[10]+=e2.z*wv; acc[11]+=e2.w*wv;
    acc[12]+=e3.x*wv; acc[13]+=e3.y*wv; acc[14]+=e3.z*wv; acc[15]+=e3.w*wv;
  }
  const int g = tid >> 8, jj = tid & 255;
  const int hb = jj >> 7, jl = jj & 127;
  const int c = g*128 + jl;
  const int wvv = c/48, rem = c - wvv*48, tt = rem >> 4, lr = rem & 15;
  #pragma unroll
  for(int r = 0; r < 16; r++){
    const int bs = r0 + r;
    const int bb = bs >> 7, s = bs & 127;
    const int kk = s >> 5, lg = (s >> 3) & 3, e = s & 7;
    const int lane = lg*16 + lr;
    encW2F[(size_t)(bb*2 + hb)*49152 + (size_t)((wvv*12 + tt*4 + kk)*64 + lane)*8 + e]
        = f2bu(acc[r]);
  }
}

// ---------------- gi_emb[t*32+b][j] = emb(tok)·W_ihT[:256, j] + b_ih[j]  (f32) ----------------
__global__ __launch_bounds__(768) void k_giemb2(const int* __restrict__ target,
    const float* __restrict__ embedding, const float* __restrict__ W_ihT,
    const float* __restrict__ b_ih, float* __restrict__ gi_emb)
{
  const int r0 = blockIdx.x*16, tid = threadIdx.x;
  __shared__ __align__(16) float embl[Hn][20];
  if(tid < Hn){
    #pragma unroll
    for(int r = 0; r < 16; r++){
      const int row = r0 + r;            // t*32+b
      const int t = row >> 5, b = row & 31;
      const int tok = (t == 0) ? 0 : target[b*Tn + (t-1)];
      embl[tid][r] = embedding[(size_t)tok*Hn + tid];
    }
  }
  __syncthreads();
  float acc[16];
  #pragma unroll
  for(int r = 0; r < 16; r++) acc[r] = b_ih[tid];
  for(int d = 0; d < Hn; d++){
    const float wv = W_ihT[(size_t)d*GIn + tid];
    const float4 e0 = *(const float4*)&embl[d][0];
    const float4 e1 = *(const float4*)&embl[d][4];
    const float4 e2 = *(const float4*)&embl[d][8];
    const float4 e3 = *(const float4*)&embl[d][12];
    acc[0]+=e0.x*wv; acc[1]+=e0.y*wv; acc[2]+=e0.z*wv; acc[3]+=e0.w*wv;
    acc[4]+=e1.x*wv; acc[5]+=e1.y*wv; acc[6]+=e1.z*wv; acc[7]+=e1.w*wv;
    acc[8]+=e2.x*wv; acc[9]+=e2.y*wv; acc[10]+=e2.z*wv; acc[11]+=e2.w*wv;
    acc[12]+=e3.x*wv; acc[13]+=e3.y*wv; acc[14]+=e3.z*wv; acc[15]+=e3.w*wv;
  }
  #pragma unroll
  for(int r = 0; r < 16; r++) gi_emb[(size_t)(r0 + r)*GIn + tid] = acc[r];
}

// ---------------- serial recurrence (r11's k_loop7, 798 µs validated) ------------
// 64 blocks, same-XCD pairs, j-split halves, ONE lockstep exchange/step
// (single-wave poll at end of step); q/phase2/softmax redundant; enc_k in
// registers; phase3 all-MFMA; q/enc_k pre-scaled by 2 for ftanh_pre.
__global__ __launch_bounds__(512, 2) void k_loop7(
    const float* __restrict__ enc_hidden,
    const unsigned short* __restrict__ ekP,        // (B,32768) packed (2x-scaled)
    const unsigned short* __restrict__ encW2F,     // (B,2,49152) frag-packed
    const unsigned short* __restrict__ W1R,        // (2,8,40,64,8)
    const float* __restrict__ Qb, const float* __restrict__ b_hh,
    const float* __restrict__ Vw, const float* __restrict__ Vb,
    const float* __restrict__ gi_emb,              // (T*B,3H) f32
    __hip_bfloat16* __restrict__ h_all,
    float* __restrict__ atts_out,
    float* __restrict__ hfin_out,
    unsigned int* hbuf,            // [2][32][2][64]
    unsigned int* hflag)           // [32][2]
{
  // same-XCD pairs: blocks bid and bid+8 share XCD under round-robin dispatch
  const int bid = blockIdx.x;
  const int hb = (bid >> 3) & 1;
  const int p  = (bid & 7) | ((bid >> 4) << 3);
  const int b = p;
  const int tid = threadIdx.x;
  const int lane = tid & 63, wv = tid >> 6;        // 8 waves
  const int lr = lane & 15, lg = lane >> 4;

  __shared__ __align__(16) unsigned short ew_l[49152];    // 96 KB encW2 frags
  __shared__ __align__(16) float h_sh[128];               // own h slice f32
  __shared__ __align__(16) short h_b16[Hn];               // full h bf16
  __shared__ __align__(16) float qgh_sh[1024];
  __shared__ __align__(16) float vw_sh[Hn];
  __shared__ __align__(16) float sc_sh[Sn];
  __shared__ __align__(16) unsigned short wb_l[Sn];
  __shared__ __align__(16) float gic_l[384];

  // ---- one-time staging ----
  {
    const unsigned short* src = encW2F + (size_t)(b*2 + hb)*49152;
    #pragma unroll
    for(int c = 0; c < 12; c++){
      const int idx = (c*512 + tid)*8;
      *(int4*)(ew_l + idx) = *(const int4*)(src + idx);
    }
  }
  bf16x8 ekr[8];
  {
    const unsigned short* esrc = ekP + (size_t)b*32768;
    #pragma unroll
    for(int i = 0; i < 8; i++)
      ekr[i] = *(const bf16x8*)(esrc + (size_t)((wv*8 + i)*64 + lane)*8);
  }
  bf16x8 w1f[40];
  {
    const unsigned short* wsrc = W1R + (((size_t)(hb*8 + wv)*40)*64 + lane)*8;
    #pragma unroll
    for(int f = 0; f < 40; f++) w1f[f] = *(const bf16x8*)(wsrc + (size_t)f*512);
  }
  float bias_r[5]; int idx_r[5];
  #pragma unroll
  for(int tt = 0; tt < 2; tt++){
    const int f = wv*32 + tt*16 + lr;
    bias_r[tt] = Qb[f]; idx_r[tt] = f;
  }
  #pragma unroll
  for(int tt = 2; tt < 5; tt++){
    const int lf = wv*48 + (tt-2)*16 + lr;
    const int g = lf >> 7, jj = lf & 127;
    bias_r[tt] = b_hh[g*256 + hb*128 + jj];
    idx_r[tt]  = 256 + g*256 + hb*128 + jj;
  }
  if(tid < Hn){
    vw_sh[tid] = Vw[tid];
    h_b16[tid] = (short)f2bu(enc_hidden[b*Hn + tid]);
  }
  if(tid < 128) h_sh[tid] = enc_hidden[b*Hn + hb*128 + tid];
  __syncthreads();
  const float vb0 = Vb[0];
  const int g2 = tid & 3;

  for(int t = 0; t < Tn; t++){
    const int par = t & 1;
    // ---- phase 1: q (redundant) + own gh slice = h @ W1.T (reg-resident weights) ----
    {
      f32x4 acc[5];
      #pragma unroll
      for(int tt = 0; tt < 5; tt++) acc[tt] = (f32x4){0.f,0.f,0.f,0.f};
      #pragma unroll
      for(int kk = 0; kk < 8; kk++){
        bf16x8 a = *(const bf16x8*)(h_b16 + kk*32 + lg*8);
        #pragma unroll
        for(int tt = 0; tt < 5; tt++)
          acc[tt] = __builtin_amdgcn_mfma_f32_16x16x32_bf16(a, w1f[kk*5 + tt], acc[tt], 0, 0, 0);
      }
      if(lane < 16){
        #pragma unroll
        for(int tt = 0; tt < 5; tt++){
          float v = acc[tt][0] + bias_r[tt];
          if(tt < 2) v *= 2.0f;          // pre-scale q by 2 for phase-2 tanh
          qgh_sh[idx_r[tt]] = v;
        }
      }
    }
    __syncthreads();                                   // b1: qgh ready

    // ---- phase 2: all 128 scores (redundant), enc_k from registers ----
    {
      float pacc = 0.f;
      #pragma unroll
      for(int i = 0; i < 8; i++){
        const bf16x8 e8 = ekr[i];
        const int kb = i*32 + g2*8;
        #pragma unroll
        for(int j = 0; j < 8; j++){
          float ev = b2f((unsigned short)e8[j]);
          pacc = fmaf(vw_sh[kb + j], ftanh_pre(qgh_sh[kb + j] + ev), pacc);
        }
      }
      pacc += __shfl_xor(pacc, 1); pacc += __shfl_xor(pacc, 2);
      if(g2 == 0) sc_sh[tid >> 2] = pacc + vb0;
    }
    __syncthreads();                                   // b2: scores ready

    // ---- softmax over S=128 (wave 0, redundant both halves) ----
    if(tid < 64){
      float v0 = sc_sh[tid], v1 = sc_sh[tid + 64];
      float m = fmaxf(v0, v1);
      #pragma unroll
      for(int off = 1; off < 64; off <<= 1) m = fmaxf(m, __shfl_xor(m, off));
      float e0 = __expf(v0 - m), e1 = __expf(v1 - m);
      float sm = e0 + e1;
      #pragma unroll
      for(int off = 1; off < 64; off <<= 1) sm += __shfl_xor(sm, off);
      float inv = frcp(sm);
      float w0 = e0*inv, w1 = e1*inv;
      wb_l[tid] = f2bu(w0); wb_l[tid + 64] = f2bu(w1);
      if(hb == 0){
        float* ao = atts_out + ((size_t)b*Tn + t)*Sn;
        ao[tid] = w0; ao[tid + 64] = w1;
      }
    }
    float ge0 = 0.f, ge1 = 0.f, ge2 = 0.f;
    if(tid < 128){
      const float* ge = gi_emb + ((size_t)t*Bn + b)*GIn + hb*128 + tid;
      ge0 = ge[0]; ge1 = ge[256]; ge2 = ge[512];
    }
    __syncthreads();                                   // b3: w ready

    // ---- phase 3: own gi_ctx (384 cols) = w @ encW2 via MFMA ----
    {
      bf16x8 wfrag[4];
      #pragma unroll
      for(int kk = 0; kk < 4; kk++)
        wfrag[kk] = *(const bf16x8*)(wb_l + kk*32 + lg*8);
      #pragma unroll
      for(int tt = 0; tt < 3; tt++){
        f32x4 a3 = (f32x4){0.f,0.f,0.f,0.f};
        #pragma unroll
        for(int kk = 0; kk < 4; kk++){
          bf16x8 bfr = *(const bf16x8*)(ew_l + (size_t)((wv*12 + tt*4 + kk)*64 + lane)*8);
          a3 = __builtin_amdgcn_mfma_f32_16x16x32_bf16(wfrag[kk], bfr, a3, 0, 0, 0);
        }
        if(lane < 16) gic_l[wv*48 + tt*16 + lane] = a3[0];
      }
    }
    __syncthreads();                                   // b4: gic ready

    // ---- phase 4: GRU own j-slice + push h-slice ----
    if(tid < 128){
      float gr = ge0 + gic_l[tid];
      float gz = ge1 + gic_l[128 + tid];
      float gn = ge2 + gic_l[256 + tid];
      const int jg = hb*128 + tid;
      float r = fsigm(gr + qgh_sh[256 + jg]);
      float z = fsigm(gz + qgh_sh[512 + jg]);
      float n = ftanh(gn + r*qgh_sh[768 + jg]);
      float hn2 = (1.0f - z)*n + z*h_sh[tid];
      h_sh[tid] = hn2;
      const unsigned short hb16 = f2bu(hn2);
      h_b16[jg] = (short)hb16;
      h_all[((size_t)t*Bn + b)*Hn + jg] = __float2bfloat16(hn2);
      if(t == Tn-1) hfin_out[b*Hn + jg] = hn2;
      if(t < Tn-1){
        float hnx = __shfl_down(hn2, 1);
        if(!(tid & 1)){
          unsigned int u = (unsigned int)hb16 | ((unsigned int)f2bu(hnx) << 16);
          st_ag_u(&hbuf[((size_t)(par*32 + p)*2 + hb)*64 + (tid >> 1)], u);
        }
      }
    }
    __syncthreads();                                   // b5: drain pushes + h_b16 own

    if(t < Tn-1){
      if(tid == 0)
        __hip_atomic_store(&hflag[p*2 + hb], (unsigned)(t + 1), __ATOMIC_RELEASE, AGENT);
      if(tid < 64){
        long cnt = 0;
        while(__hip_atomic_load(&hflag[p*2 + (hb^1)], __ATOMIC_ACQUIRE, AGENT) < (unsigned)(t + 1)
              && ++cnt < 10000000L){}
        unsigned int u = ld_ag_u(&hbuf[((size_t)(par*32 + p)*2 + (hb^1))*64 + tid]);
        ((unsigned int*)h_b16)[(hb^1)*64 + tid] = u;
      }
      __syncthreads();                                 // b6: partner h ready
    }
  }
}

// ---------------- logits GEMM: 128x128 tile, double-buffered LDS (r11) -----------
// pass 1 writes dec with NONTEMPORAL stores (write-once, bypass L2 RFO).
__global__ __launch_bounds__(256, 2) void k_lg3(
    const unsigned short* __restrict__ h_all, const unsigned short* __restrict__ w_bf,
    const float* __restrict__ out_b,
    float* __restrict__ pmax, float* __restrict__ psum,
    const float* __restrict__ lse, float* __restrict__ dec_out,
    int pass)
{
  const int tid = threadIdx.x;
  const int lane = tid & 63, w = tid >> 6;
  const int lr = lane & 15, lg = lane >> 4;
  const int wm = w >> 1, wn = w & 1;              // 2x2 waves of 64x64
  const int m0 = blockIdx.x*128;                  // 25 blocks  (3200/128)
  const int n0 = blockIdx.y*128;                  // 250 blocks (32000/128)
  const int nchunk = blockIdx.y;
  __shared__ __align__(16) unsigned short As[2][128][72];  // pad 72: 2-way-free banks
  __shared__ __align__(16) unsigned short Bs[2][128][72];
  const int srow = tid >> 2, scol = (tid & 3)*16;

  f32x4 acc[4][4];
  #pragma unroll
  for(int mt = 0; mt < 4; mt++)
    #pragma unroll
    for(int nt = 0; nt < 4; nt++) acc[mt][nt] = (f32x4){0.f,0.f,0.f,0.f};

  auto stage = [&](int buf, int ks){
    #pragma unroll
    for(int i = 0; i < 2; i++){
      const int r = i*64 + srow;
      const size_t ga = (size_t)(m0 + r)*Hn + ks*64 + scol;
      const size_t gb = (size_t)(n0 + r)*Hn + ks*64 + scol;
      int4 a0 = *(const int4*)(h_all + ga);
      int4 a1 = *(const int4*)(h_all + ga + 8);
      int4 b0 = *(const int4*)(w_bf + gb);
      int4 b1 = *(const int4*)(w_bf + gb + 8);
      *(int4*)(&As[buf][r][scol])     = a0;
      *(int4*)(&As[buf][r][scol + 8]) = a1;
      *(int4*)(&Bs[buf][r][scol])     = b0;
      *(int4*)(&Bs[buf][r][scol + 8]) = b1;
    }
  };
  auto compute = [&](int buf){
    bf16x8 am[4][2], bn[4][2];
    #pragma unroll
    for(int mt = 0; mt < 4; mt++)
      #pragma unroll
      for(int kk = 0; kk < 2; kk++)
        am[mt][kk] = *(const bf16x8*)(&As[buf][wm*64 + mt*16 + lr][kk*32 + lg*8]);
    #pragma unroll
    for(int nt = 0; nt < 4; nt++)
      #pragma unroll
      for(int kk = 0; kk < 2; kk++)
        bn[nt][kk] = *(const bf16x8*)(&Bs[buf][wn*64 + nt*16 + lr][kk*32 + lg*8]);
    #pragma unroll
    for(int kk = 0; kk < 2; kk++)
      #pragma unroll
      for(int mt = 0; mt < 4; mt++)
        #pragma unroll
        for(int nt = 0; nt < 4; nt++)
          acc[mt][nt] = __builtin_amdgcn_mfma_f32_16x16x32_bf16(am[mt][kk], bn[nt][kk], acc[mt][nt], 0, 0, 0);
  };

  stage(0, 0);
  __syncthreads();
  #pragma unroll
  for(int ks = 0; ks < 4; ks++){
    const int buf = ks & 1;
    if(ks < 3) stage(buf^1, ks+1);
    compute(buf);
    __syncthreads();
  }

  float bias[4];
  #pragma unroll
  for(int nt = 0; nt < 4; nt++) bias[nt] = out_b[n0 + wn*64 + nt*16 + lr];

  if(pass == 0){
    __shared__ float pm_l[128][2];
    __shared__ float ps_l[128][2];
    #pragma unroll
    for(int mt = 0; mt < 4; mt++){
      #pragma unroll
      for(int i = 0; i < 4; i++){
        float v0 = acc[mt][0][i] + bias[0], v1 = acc[mt][1][i] + bias[1];
        float v2 = acc[mt][2][i] + bias[2], v3 = acc[mt][3][i] + bias[3];
        float m = fmaxf(fmaxf(v0, v1), fmaxf(v2, v3));
        m = fmaxf(m, __shfl_xor(m, 1)); m = fmaxf(m, __shfl_xor(m, 2));
        m = fmaxf(m, __shfl_xor(m, 4)); m = fmaxf(m, __shfl_xor(m, 8));
        float s = __expf(v0 - m) + __expf(v1 - m) + __expf(v2 - m) + __expf(v3 - m);
        s += __shfl_xor(s, 1); s += __shfl_xor(s, 2);
        s += __shfl_xor(s, 4); s += __shfl_xor(s, 8);
        if(lr == 0){
          const int rl = wm*64 + mt*16 + lg*4 + i;
          pm_l[rl][wn] = m; ps_l[rl][wn] = s;
        }
      }
    }
    __syncthreads();
    if(tid < 128){
      float m = fmaxf(pm_l[tid][0], pm_l[tid][1]);
      float s = ps_l[tid][0]*__expf(pm_l[tid][0] - m) + ps_l[tid][1]*__expf(pm_l[tid][1] - m);
      pmax[(size_t)nchunk*3200 + m0 + tid] = m;
      psum[(size_t)nchunk*3200 + m0 + tid] = s;
    }
  } else {
    #pragma unroll
    for(int mt = 0; mt < 4; mt++){
      #pragma unroll
      for(int i = 0; i < 4; i++){
        const int rg = m0 + wm*64 + mt*16 + lg*4 + i;
        const float l = lse[rg];
        const int bb = rg & 31, tt2 = rg >> 5;
        float* dst = dec_out + (size_t)bb*((size_t)Tn*Vn) + (size_t)tt2*Vn + n0 + wn*64;
        __builtin_nontemporal_store(acc[mt][0][i] + bias[0] - l, dst +  0 + lr);
        __builtin_nontemporal_store(acc[mt][1][i] + bias[1] - l, dst + 16 + lr);
        __builtin_nontemporal_store(acc[mt][2][i] + bias[2] - l, dst + 32 + lr);
        __builtin_nontemporal_store(acc[mt][3][i] + bias[3] - l, dst + 48 + lr);
      }
    }
  }
}

// ---------------- lse combine: 4 threads/row, shuffle-combine ----------------
__global__ __launch_bounds__(256) void k_lse2(const float* __restrict__ pmax,
    const float* __restrict__ psum, float* __restrict__ lse)
{
  const int row = blockIdx.x*64 + (threadIdx.x >> 2);   // 50 blocks x 64 rows
  const int q = threadIdx.x & 3;
  float m = -3.0e38f;
  for(int c = q; c < 250; c += 4) m = fmaxf(m, pmax[(size_t)c*3200 + row]);
  float mg = m;
  mg = fmaxf(mg, __shfl_xor(mg, 1));
  mg = fmaxf(mg, __shfl_xor(mg, 2));
  float s = 0.f;
  for(int c = q; c < 250; c += 4)
    s += psum[(size_t)c*3200 + row] * __expf(pmax[(size_t)c*3200 + row] - mg);
  s += __shfl_xor(s, 1);
  s += __shfl_xor(s, 2);
  if(q == 0) lse[row] = mg + __logf(s);
}

// ---------------- launch ----------------
extern "C" void kernel_launch(void* const* d_in, const int* in_sizes, int n_in,
                              void* d_out, int out_size, void* d_ws, size_t ws_size,
                              hipStream_t stream)
{
  const float* enc_outputs = (const float*)d_in[0];
  const float* enc_hidden  = (const float*)d_in[1];
  const int*   target      = (const int*)d_in[2];
  const float* embedding   = (const float*)d_in[3];
  const float* Qw   = (const float*)d_in[4];
  const float* Qb   = (const float*)d_in[5];
  const float* Kw   = (const float*)d_in[6];
  const float* Kb   = (const float*)d_in[7];
  const float* Vw   = (const float*)d_in[8];
  const float* Vb   = (const float*)d_in[9];
  const float* W_ih = (const float*)d_in[10];
  const float* W_hh = (const float*)d_in[11];
  const float* b_ih = (const float*)d_in[12];
  const float* b_hh = (const float*)d_in[13];
  const float* out_w = (const float*)d_in[14];
  const float* out_b = (const float*)d_in[15];

  float* dec  = (float*)d_out;                       // (B,T,V)
  float* hfin = dec + (size_t)Bn*Tn*Vn;              // (1,B,H)
  float* atts = hfin + Bn*Hn;                        // (B,T,S)

  // Scratch inside dec region (fully consumed before pass-1 overwrites):
  unsigned short* enc_kb16 = (unsigned short*)(dec);            // 524,288 f32 slots
  unsigned short* ekP      = (unsigned short*)(dec + 524288);   // 524,288
  unsigned short* encW2F   = (unsigned short*)(dec + 1048576);  // 1,572,864
  float* gi_emb = dec + 2621440;                                // 2,457,600
  float* W_ihT  = dec + 5079040;                                // 393,216
  float* KwT    = dec + 5472256;                                // 65,536
  float* pmax   = dec + 5537792;                                // 800,000 (250x3200)
  float* psum   = dec + 6337792;                                // 800,000
  unsigned short* W1R = (unsigned short*)(dec + 7137792);       // 163,840 f32 slots
  unsigned int* hbuf  = (unsigned int*)(dec + 7301632);         // 8,192
  unsigned int* hflag = (unsigned int*)(dec + 7309824);         // 64 (ends 7,309,888)

  // ws: lse + h_all(bf16) + out_w(bf16)
  float* wsf = (float*)d_ws;
  float* lse = wsf;
  __hip_bfloat16* h_all = (__hip_bfloat16*)(wsf + 3200);
  __hip_bfloat16* w_bf  = h_all + (size_t)Tn*Bn*Hn;

  // prep
  k_tr     <<<dim3(8, 8),   dim3(256), 0, stream>>>(Kw, KwT, 256, 256);
  k_tr     <<<dim3(16, 24), dim3(256), 0, stream>>>(W_ih, W_ihT, 768, 512);
  k_packW1R<<<dim3(160),    dim3(256), 0, stream>>>(Qw, W_hh, W1R);
  k_cvt    <<<dim3((Vn*Hn)/1024), dim3(256), 0, stream>>>(out_w, w_bf, Vn*Hn);
  k_enc2   <<<dim3(256), dim3(256), 0, stream>>>(enc_outputs, KwT, Kb, enc_kb16);
  k_packEk <<<dim3(512), dim3(256), 0, stream>>>(enc_kb16, ekP);
  k_encW2F <<<dim3(256), dim3(768), 0, stream>>>(enc_outputs, W_ihT, encW2F);
  k_giemb2 <<<dim3(200), dim3(768), 0, stream>>>(target, embedding, W_ihT, b_ih, gi_emb);

  // reset flags (stream-ordered before k_loop7)
  hipMemsetAsync((void*)hflag, 0, 64*sizeof(unsigned int), stream);

  // recurrence: 64 co-resident blocks, one lockstep exchange/step
  k_loop7 <<<dim3(64), dim3(512), 0, stream>>>(enc_hidden, ekP, encW2F, W1R,
            Qb, b_hh, Vw, Vb, gi_emb, h_all, atts, hfin, hbuf, hflag);

  // logits + log_softmax (staged GEMM; grid = (m, n) for B-strip L2 reuse)
  k_lg3   <<<dim3(25, 250), dim3(256), 0, stream>>>(
            (const unsigned short*)h_all, (const unsigned short*)w_bf, out_b,
            pmax, psum, (const float*)nullptr, (float*)nullptr, 0);
  k_lse2  <<<dim3(50), dim3(256), 0, stream>>>(pmax, psum, lse);
  k_lg3   <<<dim3(25, 250), dim3(256), 0, stream>>>(
            (const unsigned short*)h_all, (const unsigned short*)w_bf, out_b,
            (float*)nullptr, (float*)nullptr, lse, dec, 1);
}

// Round 14
// 1173.559 us; speedup vs baseline: 1.5271x; 1.0065x over previous
//
#include <hip/hip_runtime.h>
#include <hip/hip_bf16.h>

// Decoder: B=32, S=128, H=256, V=32000, T=100
#define Bn 32
#define Sn 128
#define Hn 256
#define Vn 32000
#define Tn 100
#define GIn 768   // 3H
#define AGENT __HIP_MEMORY_SCOPE_AGENT

typedef __attribute__((ext_vector_type(8))) short bf16x8;
typedef __attribute__((ext_vector_type(4))) float f32x4;

__device__ __forceinline__ float frcp(float x){ return __builtin_amdgcn_rcpf(x); }
__device__ __forceinline__ float ftanh(float x){ return 1.0f - 2.0f*frcp(__expf(2.0f*x)+1.0f); }
// input pre-scaled by 2: tanh(x) given y=2x
__device__ __forceinline__ float ftanh_pre(float y){ return 1.0f - 2.0f*frcp(__expf(y)+1.0f); }
__device__ __forceinline__ float fsigm(float x){ return frcp(1.0f + __expf(-x)); }
__device__ __forceinline__ float b2f(unsigned short u){
  unsigned int v = ((unsigned int)u) << 16; return __builtin_bit_cast(float, v);
}
__device__ __forceinline__ unsigned short f2bu(float f){ // RNE f32->bf16 bits
  unsigned int u = __builtin_bit_cast(unsigned int, f);
  u += 0x7FFFu + ((u >> 16) & 1u);
  return (unsigned short)(u >> 16);
}
__device__ __forceinline__ void st_ag_u(unsigned int* p, unsigned int v){
  __hip_atomic_store(p, v, __ATOMIC_RELAXED, AGENT);
}
__device__ __forceinline__ unsigned int ld_ag_u(unsigned int* p){
  return __hip_atomic_load(p, __ATOMIC_RELAXED, AGENT);
}

// ---------------- generic 32x32 tiled transpose: out(CxR) = in(RxC)^T ----------------
__global__ __launch_bounds__(256) void k_tr(const float* __restrict__ in,
    float* __restrict__ out, int R, int C)
{
  __shared__ float tile[32][33];
  const int bx = blockIdx.x*32, by = blockIdx.y*32;
  const int tx = threadIdx.x & 31, ty = threadIdx.x >> 5;
  #pragma unroll
  for(int r = ty; r < 32; r += 8)
    if(by + r < R && bx + tx < C) tile[r][tx] = in[(size_t)(by + r)*C + bx + tx];
  __syncthreads();
  #pragma unroll
  for(int r = ty; r < 32; r += 8)
    if(bx + r < C && by + tx < R) out[(size_t)(bx + r)*R + by + tx] = tile[tx][r];
}

// ---------------- W1R: per-(half,wave) MFMA B-fragments (validated r6-r13) -------
__global__ __launch_bounds__(256) void k_packW1R(const float* __restrict__ Qw,
    const float* __restrict__ Whh, unsigned short* __restrict__ W1R)
{
  const int tid = blockIdx.x*256 + threadIdx.x;   // 0..40959
  const int lane = tid & 63;
  const int fragid = tid >> 6;                    // 0..639
  const int tt = fragid % 5;
  const int kk = (fragid/5) % 8;
  const int w  = (fragid/40) % 8;
  const int hb = fragid/320;
  const int lr = lane & 15, lg = lane >> 4;
  const float* src;
  if(tt < 2){
    const int f = w*32 + tt*16 + lr;
    src = Qw + (size_t)f*Hn;
  } else {
    const int lf = w*48 + (tt-2)*16 + lr;
    const int g = lf >> 7, jj = lf & 127;
    src = Whh + (size_t)(g*256 + hb*128 + jj)*Hn;
  }
  const int col = kk*32 + lg*8;
  float4 v0 = *(const float4*)(src + col), v1 = *(const float4*)(src + col + 4);
  unsigned short* d = W1R + ((size_t)fragid*64 + lane)*8;
  d[0]=f2bu(v0.x); d[1]=f2bu(v0.y); d[2]=f2bu(v0.z); d[3]=f2bu(v0.w);
  d[4]=f2bu(v1.x); d[5]=f2bu(v1.y); d[6]=f2bu(v1.z); d[7]=f2bu(v1.w);
}

// f32 -> bf16 (out_w), nontemporal read (64 MB read-once stream)
__global__ __launch_bounds__(256) void k_cvt(const float* __restrict__ src,
    __hip_bfloat16* __restrict__ dst, int n)
{
  int i = (blockIdx.x*256 + threadIdx.x)*4;
  if(i < n){
    float4 v;
    v.x = __builtin_nontemporal_load(src + i);
    v.y = __builtin_nontemporal_load(src + i + 1);
    v.z = __builtin_nontemporal_load(src + i + 2);
    v.w = __builtin_nontemporal_load(src + i + 3);
    dst[i+0] = __float2bfloat16(v.x);
    dst[i+1] = __float2bfloat16(v.y);
    dst[i+2] = __float2bfloat16(v.z);
    dst[i+3] = __float2bfloat16(v.w);
  }
}

// ---------------- enc_kb16[bs][j] = bf16( 2*(enc[bs,:]·KwT[:,j] + Kb[j]) ) -------
__global__ __launch_bounds__(256) void k_enc2(const float* __restrict__ enc_outputs,
    const float* __restrict__ KwT, const float* __restrict__ Kb,
    unsigned short* __restrict__ enc_kb16)
{
  const int r0 = blockIdx.x*16, j = threadIdx.x;
  __shared__ __align__(16) float encl[Hn][20];
  #pragma unroll
  for(int r = 0; r < 16; r++) encl[j][r] = enc_outputs[(size_t)(r0 + r)*Hn + j];
  __syncthreads();
  float acc[16];
  #pragma unroll
  for(int r = 0; r < 16; r++) acc[r] = Kb[j];
  for(int d = 0; d < Hn; d++){
    const float wv = KwT[(size_t)d*Hn + j];
    const float4 e0 = *(const float4*)&encl[d][0];
    const float4 e1 = *(const float4*)&encl[d][4];
    const float4 e2 = *(const float4*)&encl[d][8];
    const float4 e3 = *(const float4*)&encl[d][12];
    acc[0]+=e0.x*wv; acc[1]+=e0.y*wv; acc[2]+=e0.z*wv; acc[3]+=e0.w*wv;
    acc[4]+=e1.x*wv; acc[5]+=e1.y*wv; acc[6]+=e1.z*wv; acc[7]+=e1.w*wv;
    acc[8]+=e2.x*wv; acc[9]+=e2.y*wv; acc[10]+=e2.z*wv; acc[11]+=e2.w*wv;
    acc[12]+=e3.x*wv; acc[13]+=e3.y*wv; acc[14]+=e3.z*wv; acc[15]+=e3.w*wv;
  }
  #pragma unroll
  for(int r = 0; r < 16; r++) enc_kb16[(size_t)(r0 + r)*Hn + j] = f2bu(2.0f*acc[r]);
}

// ---------------- ekP: enc_k permuted to phase-2 consumption order (validated) ----
__global__ __launch_bounds__(256) void k_packEk(const unsigned short* __restrict__ enc_kb16,
    unsigned short* __restrict__ ekP)
{
  const int tid = blockIdx.x*256 + threadIdx.x;   // 0..131071
  const int b = tid >> 12;
  const int o = tid & 4095;
  const int g = o >> 6, l = o & 63;
  const int w = g >> 3, i = g & 7;
  const int s = w*16 + (l >> 2);
  const int e0 = i*32 + (l & 3)*8;
  const int4 v = *(const int4*)(enc_kb16 + ((size_t)(b*Sn + s))*Hn + e0);
  *(int4*)(ekP + (size_t)b*32768 + (size_t)o*8) = v;
}

// ---------------- encW2F: MFMA B-fragment layout per (b, hb) (validated) ---------
__global__ __launch_bounds__(768) void k_encW2F(const float* __restrict__ enc_outputs,
    const float* __restrict__ W_ihT, unsigned short* __restrict__ encW2F)
{
  const int r0 = blockIdx.x*16, tid = threadIdx.x;   // tid = j
  __shared__ __align__(16) float encl[Hn][20];
  if(tid < Hn){
    #pragma unroll
    for(int r = 0; r < 16; r++) encl[tid][r] = enc_outputs[(size_t)(r0 + r)*Hn + tid];
  }
  __syncthreads();
  float acc[16];
  #pragma unroll
  for(int r = 0; r < 16; r++) acc[r] = 0.f;
  for(int d = 0; d < Hn; d++){
    const float wv = W_ihT[(size_t)(Hn + d)*GIn + tid];
    const float4 e0 = *(const float4*)&encl[d][0];
    const float4 e1 = *(const float4*)&encl[d][4];
    const float4 e2 = *(const float4*)&encl[d][8];
    const float4 e3 = *(const float4*)&encl[d][12];
    acc[0]+=e0.x*wv; acc[1]+=e0.y*wv; acc[2]+=e0.z*wv; acc[3]+=e0.w*wv;
    acc[4]+=e1.x*wv; acc[5]+=e1.y*wv; acc[6]+=e1.z*wv; acc[7]+=e1.w*wv;
    acc[8]+=e2.x*wv; acc[9]+=e2.y*wv; acc[10]+=e2.z*wv; acc[11]+=e2.w*wv;
    acc[12]+=e3.x*wv; acc[13]+=e3.y*wv; acc[14]+=e3.z*wv; acc[15]+=e3.w*wv;
  }
  const int g = tid >> 8, jj = tid & 255;
  const int hb = jj >> 7, jl = jj & 127;
  const int c = g*128 + jl;
  const int wvv = c/48, rem = c - wvv*48, tt = rem >> 4, lr = rem & 15;
  #pragma unroll
  for(int r = 0; r < 16; r++){
    const int bs = r0 + r;
    const int bb = bs >> 7, s = bs & 127;
    const int kk = s >> 5, lg = (s >> 3) & 3, e = s & 7;
    const int lane = lg*16 + lr;
    encW2F[(size_t)(bb*2 + hb)*49152 + (size_t)((wvv*12 + tt*4 + kk)*64 + lane)*8 + e]
        = f2bu(acc[r]);
  }
}

// ---------------- gi_emb[t*32+b][j] = emb(tok)·W_ihT[:256, j] + b_ih[j]  (f32) ----------------
__global__ __launch_bounds__(768) void k_giemb2(const int* __restrict__ target,
    const float* __restrict__ embedding, const float* __restrict__ W_ihT,
    const float* __restrict__ b_ih, float* __restrict__ gi_emb)
{
  const int r0 = blockIdx.x*16, tid = threadIdx.x;
  __shared__ __align__(16) float embl[Hn][20];
  if(tid < Hn){
    #pragma unroll
    for(int r = 0; r < 16; r++){
      const int row = r0 + r;            // t*32+b
      const int t = row >> 5, b = row & 31;
      const int tok = (t == 0) ? 0 : target[b*Tn + (t-1)];
      embl[tid][r] = embedding[(size_t)tok*Hn + tid];
    }
  }
  __syncthreads();
  float acc[16];
  #pragma unroll
  for(int r = 0; r < 16; r++) acc[r] = b_ih[tid];
  for(int d = 0; d < Hn; d++){
    const float wv = W_ihT[(size_t)d*GIn + tid];
    const float4 e0 = *(const float4*)&embl[d][0];
    const float4 e1 = *(const float4*)&embl[d][4];
    const float4 e2 = *(const float4*)&embl[d][8];
    const float4 e3 = *(const float4*)&embl[d][12];
    acc[0]+=e0.x*wv; acc[1]+=e0.y*wv; acc[2]+=e0.z*wv; acc[3]+=e0.w*wv;
    acc[4]+=e1.x*wv; acc[5]+=e1.y*wv; acc[6]+=e1.z*wv; acc[7]+=e1.w*wv;
    acc[8]+=e2.x*wv; acc[9]+=e2.y*wv; acc[10]+=e2.z*wv; acc[11]+=e2.w*wv;
    acc[12]+=e3.x*wv; acc[13]+=e3.y*wv; acc[14]+=e3.z*wv; acc[15]+=e3.w*wv;
  }
  #pragma unroll
  for(int r = 0; r < 16; r++) gi_emb[(size_t)(r0 + r)*GIn + tid] = acc[r];
}

// ---------------- serial recurrence: r13's k_loop7 with b3 removed ---------------
// Softmax is computed redundantly by ALL 8 waves (identical shuffle math); w is
// broadcast via a wave-private 128-entry LDS scratch (same-wave ds_write->ds_read,
// ordered by lgkmcnt, NO barrier). 5 barriers/step instead of 6.
__global__ __launch_bounds__(512, 2) void k_loop10(
    const float* __restrict__ enc_hidden,
    const unsigned short* __restrict__ ekP,        // (B,32768) packed (2x-scaled)
    const unsigned short* __restrict__ encW2F,     // (B,2,49152) frag-packed
    const unsigned short* __restrict__ W1R,        // (2,8,40,64,8)
    const float* __restrict__ Qb, const float* __restrict__ b_hh,
    const float* __restrict__ Vw, const float* __restrict__ Vb,
    const float* __restrict__ gi_emb,              // (T*B,3H) f32
    __hip_bfloat16* __restrict__ h_all,
    float* __restrict__ atts_out,
    float* __restrict__ hfin_out,
    unsigned int* hbuf,            // [2][32][2][64]
    unsigned int* hflag)           // [32][2]
{
  // same-XCD pairs: blocks bid and bid+8 share XCD under round-robin dispatch
  const int bid = blockIdx.x;
  const int hb = (bid >> 3) & 1;
  const int p  = (bid & 7) | ((bid >> 4) << 3);
  const int b = p;
  const int tid = threadIdx.x;
  const int lane = tid & 63, wv = tid >> 6;        // 8 waves
  const int lr = lane & 15, lg = lane >> 4;

  __shared__ __align__(16) unsigned short ew_l[49152];    // 96 KB encW2 frags
  __shared__ __align__(16) float h_sh[128];               // own h slice f32
  __shared__ __align__(16) short h_b16[Hn];               // full h bf16
  __shared__ __align__(16) float qgh_sh[1024];
  __shared__ __align__(16) float vw_sh[Hn];
  __shared__ __align__(16) float sc_sh[Sn];
  __shared__ __align__(16) unsigned short wb_w[8*128];    // wave-private w scratch
  __shared__ __align__(16) float gic_l[384];

  // ---- one-time staging ----
  {
    const unsigned short* src = encW2F + (size_t)(b*2 + hb)*49152;
    #pragma unroll
    for(int c = 0; c < 12; c++){
      const int idx = (c*512 + tid)*8;
      *(int4*)(ew_l + idx) = *(const int4*)(src + idx);
    }
  }
  bf16x8 ekr[8];
  {
    const unsigned short* esrc = ekP + (size_t)b*32768;
    #pragma unroll
    for(int i = 0; i < 8; i++)
      ekr[i] = *(const bf16x8*)(esrc + (size_t)((wv*8 + i)*64 + lane)*8);
  }
  bf16x8 w1f[40];
  {
    const unsigned short* wsrc = W1R + (((size_t)(hb*8 + wv)*40)*64 + lane)*8;
    #pragma unroll
    for(int f = 0; f < 40; f++) w1f[f] = *(const bf16x8*)(wsrc + (size_t)f*512);
  }
  float bias_r[5]; int idx_r[5];
  #pragma unroll
  for(int tt = 0; tt < 2; tt++){
    const int f = wv*32 + tt*16 + lr;
    bias_r[tt] = Qb[f]; idx_r[tt] = f;
  }
  #pragma unroll
  for(int tt = 2; tt < 5; tt++){
    const int lf = wv*48 + (tt-2)*16 + lr;
    const int g = lf >> 7, jj = lf & 127;
    bias_r[tt] = b_hh[g*256 + hb*128 + jj];
    idx_r[tt]  = 256 + g*256 + hb*128 + jj;
  }
  if(tid < Hn){
    vw_sh[tid] = Vw[tid];
    h_b16[tid] = (short)f2bu(enc_hidden[b*Hn + tid]);
  }
  if(tid < 128) h_sh[tid] = enc_hidden[b*Hn + hb*128 + tid];
  __syncthreads();
  const float vb0 = Vb[0];
  const int g2 = tid & 3;

  for(int t = 0; t < Tn; t++){
    const int par = t & 1;
    // ---- phase 1: q (redundant) + own gh slice = h @ W1.T (reg-resident weights) ----
    {
      f32x4 acc[5];
      #pragma unroll
      for(int tt = 0; tt < 5; tt++) acc[tt] = (f32x4){0.f,0.f,0.f,0.f};
      #pragma unroll
      for(int kk = 0; kk < 8; kk++){
        bf16x8 a = *(const bf16x8*)(h_b16 + kk*32 + lg*8);
        #pragma unroll
        for(int tt = 0; tt < 5; tt++)
          acc[tt] = __builtin_amdgcn_mfma_f32_16x16x32_bf16(a, w1f[kk*5 + tt], acc[tt], 0, 0, 0);
      }
      if(lane < 16){
        #pragma unroll
        for(int tt = 0; tt < 5; tt++){
          float v = acc[tt][0] + bias_r[tt];
          if(tt < 2) v *= 2.0f;          // pre-scale q by 2 for phase-2 tanh
          qgh_sh[idx_r[tt]] = v;
        }
      }
    }
    __syncthreads();                                   // b1: qgh ready

    // ---- phase 2: all 128 scores (redundant), enc_k from registers ----
    {
      float pacc = 0.f;
      #pragma unroll
      for(int i = 0; i < 8; i++){
        const bf16x8 e8 = ekr[i];
        const int kb = i*32 + g2*8;
        #pragma unroll
        for(int j = 0; j < 8; j++){
          float ev = b2f((unsigned short)e8[j]);
          pacc = fmaf(vw_sh[kb + j], ftanh_pre(qgh_sh[kb + j] + ev), pacc);
        }
      }
      pacc += __shfl_xor(pacc, 1); pacc += __shfl_xor(pacc, 2);
      if(g2 == 0) sc_sh[tid >> 2] = pacc + vb0;
    }
    __syncthreads();                                   // b2: scores ready

    // ---- softmax over S=128 (ALL waves redundantly; wave-local broadcast) ----
    float w0, w1;
    {
      float v0 = sc_sh[lane], v1 = sc_sh[lane + 64];
      float m = fmaxf(v0, v1);
      #pragma unroll
      for(int off = 1; off < 64; off <<= 1) m = fmaxf(m, __shfl_xor(m, off));
      float e0 = __expf(v0 - m), e1 = __expf(v1 - m);
      float sm = e0 + e1;
      #pragma unroll
      for(int off = 1; off < 64; off <<= 1) sm += __shfl_xor(sm, off);
      float inv = frcp(sm);
      w0 = e0*inv; w1 = e1*inv;
      unsigned short* wb = wb_w + wv*128;
      wb[lane] = f2bu(w0); wb[lane + 64] = f2bu(w1);   // same-wave produce
    }
    if(hb == 0 && tid < 64){
      float* ao = atts_out + ((size_t)b*Tn + t)*Sn;
      ao[tid] = w0; ao[tid + 64] = w1;
    }
    float ge0 = 0.f, ge1 = 0.f, ge2 = 0.f;
    if(tid < 128){
      const float* ge = gi_emb + ((size_t)t*Bn + b)*GIn + hb*128 + tid;
      ge0 = ge[0]; ge1 = ge[256]; ge2 = ge[512];
    }
    // (no barrier: wb_w[wv] is same-wave data, ordered by lgkmcnt)

    // ---- phase 3: own gi_ctx (384 cols) = w @ encW2 via MFMA ----
    {
      bf16x8 wfrag[4];
      #pragma unroll
      for(int kk = 0; kk < 4; kk++)
        wfrag[kk] = *(const bf16x8*)(wb_w + wv*128 + kk*32 + lg*8);
      #pragma unroll
      for(int tt = 0; tt < 3; tt++){
        f32x4 a3 = (f32x4){0.f,0.f,0.f,0.f};
        #pragma unroll
        for(int kk = 0; kk < 4; kk++){
          bf16x8 bfr = *(const bf16x8*)(ew_l + (size_t)((wv*12 + tt*4 + kk)*64 + lane)*8);
          a3 = __builtin_amdgcn_mfma_f32_16x16x32_bf16(wfrag[kk], bfr, a3, 0, 0, 0);
        }
        if(lane < 16) gic_l[wv*48 + tt*16 + lane] = a3[0];
      }
    }
    __syncthreads();                                   // b4: gic ready

    // ---- phase 4: GRU own j-slice + push h-slice ----
    if(tid < 128){
      float gr = ge0 + gic_l[tid];
      float gz = ge1 + gic_l[128 + tid];
      float gn = ge2 + gic_l[256 + tid];
      const int jg = hb*128 + tid;
      float r = fsigm(gr + qgh_sh[256 + jg]);
      float z = fsigm(gz + qgh_sh[512 + jg]);
      float n = ftanh(gn + r*qgh_sh[768 + jg]);
      float hn2 = (1.0f - z)*n + z*h_sh[tid];
      h_sh[tid] = hn2;
      const unsigned short hb16 = f2bu(hn2);
      h_b16[jg] = (short)hb16;
      h_all[((size_t)t*Bn + b)*Hn + jg] = __float2bfloat16(hn2);
      if(t == Tn-1) hfin_out[b*Hn + jg] = hn2;
      if(t < Tn-1){
        float hnx = __shfl_down(hn2, 1);
        if(!(tid & 1)){
          unsigned int u = (unsigned int)hb16 | ((unsigned int)f2bu(hnx) << 16);
          st_ag_u(&hbuf[((size_t)(par*32 + p)*2 + hb)*64 + (tid >> 1)], u);
        }
      }
    }
    __syncthreads();                                   // b5: drain pushes + h_b16 own

    if(t < Tn-1){
      if(tid == 0)
        __hip_atomic_store(&hflag[p*2 + hb], (unsigned)(t + 1), __ATOMIC_RELEASE, AGENT);
      if(tid < 64){
        long cnt = 0;
        while(__hip_atomic_load(&hflag[p*2 + (hb^1)], __ATOMIC_ACQUIRE, AGENT) < (unsigned)(t + 1)
              && ++cnt < 10000000L){}
        unsigned int u = ld_ag_u(&hbuf[((size_t)(par*32 + p)*2 + (hb^1))*64 + tid]);
        ((unsigned int*)h_b16)[(hb^1)*64 + tid] = u;
      }
      __syncthreads();                                 // b6: partner h ready
    }
  }
}

// ---------------- logits GEMM: 128x128 tile, double-buffered LDS (r11/r13) -------
// pass 1 writes dec with NONTEMPORAL stores (write-once, bypass L2 RFO).
__global__ __launch_bounds__(256, 2) void k_lg3(
    const unsigned short* __restrict__ h_all, const unsigned short* __restrict__ w_bf,
    const float* __restrict__ out_b,
    float* __restrict__ pmax, float* __restrict__ psum,
    const float* __restrict__ lse, float* __restrict__ dec_out,
    int pass)
{
  const int tid = threadIdx.x;
  const int lane = tid & 63, w = tid >> 6;
  const int lr = lane & 15, lg = lane >> 4;
  const int wm = w >> 1, wn = w & 1;              // 2x2 waves of 64x64
  const int m0 = blockIdx.x*128;                  // 25 blocks  (3200/128)
  const int n0 = blockIdx.y*128;                  // 250 blocks (32000/128)
  const int nchunk = blockIdx.y;
  __shared__ __align__(16) unsigned short As[2][128][72];  // pad 72: 2-way-free banks
  __shared__ __align__(16) unsigned short Bs[2][128][72];
  const int srow = tid >> 2, scol = (tid & 3)*16;

  f32x4 acc[4][4];
  #pragma unroll
  for(int mt = 0; mt < 4; mt++)
    #pragma unroll
    for(int nt = 0; nt < 4; nt++) acc[mt][nt] = (f32x4){0.f,0.f,0.f,0.f};

  auto stage = [&](int buf, int ks){
    #pragma unroll
    for(int i = 0; i < 2; i++){
      const int r = i*64 + srow;
      const size_t ga = (size_t)(m0 + r)*Hn + ks*64 + scol;
      const size_t gb = (size_t)(n0 + r)*Hn + ks*64 + scol;
      int4 a0 = *(const int4*)(h_all + ga);
      int4 a1 = *(const int4*)(h_all + ga + 8);
      int4 b0 = *(const int4*)(w_bf + gb);
      int4 b1 = *(const int4*)(w_bf + gb + 8);
      *(int4*)(&As[buf][r][scol])     = a0;
      *(int4*)(&As[buf][r][scol + 8]) = a1;
      *(int4*)(&Bs[buf][r][scol])     = b0;
      *(int4*)(&Bs[buf][r][scol + 8]) = b1;
    }
  };
  auto compute = [&](int buf){
    bf16x8 am[4][2], bn[4][2];
    #pragma unroll
    for(int mt = 0; mt < 4; mt++)
      #pragma unroll
      for(int kk = 0; kk < 2; kk++)
        am[mt][kk] = *(const bf16x8*)(&As[buf][wm*64 + mt*16 + lr][kk*32 + lg*8]);
    #pragma unroll
    for(int nt = 0; nt < 4; nt++)
      #pragma unroll
      for(int kk = 0; kk < 2; kk++)
        bn[nt][kk] = *(const bf16x8*)(&Bs[buf][wn*64 + nt*16 + lr][kk*32 + lg*8]);
    #pragma unroll
    for(int kk = 0; kk < 2; kk++)
      #pragma unroll
      for(int mt = 0; mt < 4; mt++)
        #pragma unroll
        for(int nt = 0; nt < 4; nt++)
          acc[mt][nt] = __builtin_amdgcn_mfma_f32_16x16x32_bf16(am[mt][kk], bn[nt][kk], acc[mt][nt], 0, 0, 0);
  };

  stage(0, 0);
  __syncthreads();
  #pragma unroll
  for(int ks = 0; ks < 4; ks++){
    const int buf = ks & 1;
    if(ks < 3) stage(buf^1, ks+1);
    compute(buf);
    __syncthreads();
  }

  float bias[4];
  #pragma unroll
  for(int nt = 0; nt < 4; nt++) bias[nt] = out_b[n0 + wn*64 + nt*16 + lr];

  if(pass == 0){
    __shared__ float pm_l[128][2];
    __shared__ float ps_l[128][2];
    #pragma unroll
    for(int mt = 0; mt < 4; mt++){
      #pragma unroll
      for(int i = 0; i < 4; i++){
        float v0 = acc[mt][0][i] + bias[0], v1 = acc[mt][1][i] + bias[1];
        float v2 = acc[mt][2][i] + bias[2], v3 = acc[mt][3][i] + bias[3];
        float m = fmaxf(fmaxf(v0, v1), fmaxf(v2, v3));
        m = fmaxf(m, __shfl_xor(m, 1)); m = fmaxf(m, __shfl_xor(m, 2));
        m = fmaxf(m, __shfl_xor(m, 4)); m = fmaxf(m, __shfl_xor(m, 8));
        float s = __expf(v0 - m) + __expf(v1 - m) + __expf(v2 - m) + __expf(v3 - m);
        s += __shfl_xor(s, 1); s += __shfl_xor(s, 2);
        s += __shfl_xor(s, 4); s += __shfl_xor(s, 8);
        if(lr == 0){
          const int rl = wm*64 + mt*16 + lg*4 + i;
          pm_l[rl][wn] = m; ps_l[rl][wn] = s;
        }
      }
    }
    __syncthreads();
    if(tid < 128){
      float m = fmaxf(pm_l[tid][0], pm_l[tid][1]);
      float s = ps_l[tid][0]*__expf(pm_l[tid][0] - m) + ps_l[tid][1]*__expf(pm_l[tid][1] - m);
      pmax[(size_t)nchunk*3200 + m0 + tid] = m;
      psum[(size_t)nchunk*3200 + m0 + tid] = s;
    }
  } else {
    #pragma unroll
    for(int mt = 0; mt < 4; mt++){
      #pragma unroll
      for(int i = 0; i < 4; i++){
        const int rg = m0 + wm*64 + mt*16 + lg*4 + i;
        const float l = lse[rg];
        const int bb = rg & 31, tt2 = rg >> 5;
        float* dst = dec_out + (size_t)bb*((size_t)Tn*Vn) + (size_t)tt2*Vn + n0 + wn*64;
        __builtin_nontemporal_store(acc[mt][0][i] + bias[0] - l, dst +  0 + lr);
        __builtin_nontemporal_store(acc[mt][1][i] + bias[1] - l, dst + 16 + lr);
        __builtin_nontemporal_store(acc[mt][2][i] + bias[2] - l, dst + 32 + lr);
        __builtin_nontemporal_store(acc[mt][3][i] + bias[3] - l, dst + 48 + lr);
      }
    }
  }
}

// ---------------- lse combine: 4 threads/row, shuffle-combine ----------------
__global__ __launch_bounds__(256) void k_lse2(const float* __restrict__ pmax,
    const float* __restrict__ psum, float* __restrict__ lse)
{
  const int row = blockIdx.x*64 + (threadIdx.x >> 2);   // 50 blocks x 64 rows
  const int q = threadIdx.x & 3;
  float m = -3.0e38f;
  for(int c = q; c < 250; c += 4) m = fmaxf(m, pmax[(size_t)c*3200 + row]);
  float mg = m;
  mg = fmaxf(mg, __shfl_xor(mg, 1));
  mg = fmaxf(mg, __shfl_xor(mg, 2));
  float s = 0.f;
  for(int c = q; c < 250; c += 4)
    s += psum[(size_t)c*3200 + row] * __expf(pmax[(size_t)c*3200 + row] - mg);
  s += __shfl_xor(s, 1);
  s += __shfl_xor(s, 2);
  if(q == 0) lse[row] = mg + __logf(s);
}

// ---------------- launch ----------------
extern "C" void kernel_launch(void* const* d_in, const int* in_sizes, int n_in,
                              void* d_out, int out_size, void* d_ws, size_t ws_size,
                              hipStream_t stream)
{
  const float* enc_outputs = (const float*)d_in[0];
  const float* enc_hidden  = (const float*)d_in[1];
  const int*   target      = (const int*)d_in[2];
  const float* embedding   = (const float*)d_in[3];
  const float* Qw   = (const float*)d_in[4];
  const float* Qb   = (const float*)d_in[5];
  const float* Kw   = (const float*)d_in[6];
  const float* Kb   = (const float*)d_in[7];
  const float* Vw   = (const float*)d_in[8];
  const float* Vb   = (const float*)d_in[9];
  const float* W_ih = (const float*)d_in[10];
  const float* W_hh = (const float*)d_in[11];
  const float* b_ih = (const float*)d_in[12];
  const float* b_hh = (const float*)d_in[13];
  const float* out_w = (const float*)d_in[14];
  const float* out_b = (const float*)d_in[15];

  float* dec  = (float*)d_out;                       // (B,T,V)
  float* hfin = dec + (size_t)Bn*Tn*Vn;              // (1,B,H)
  float* atts = hfin + Bn*Hn;                        // (B,T,S)

  // Scratch inside dec region (fully consumed before pass-1 overwrites):
  unsigned short* enc_kb16 = (unsigned short*)(dec);            // 524,288 f32 slots
  unsigned short* ekP      = (unsigned short*)(dec + 524288);   // 524,288
  unsigned short* encW2F   = (unsigned short*)(dec + 1048576);  // 1,572,864
  float* gi_emb = dec + 2621440;                                // 2,457,600
  float* W_ihT  = dec + 5079040;                                // 393,216
  float* KwT    = dec + 5472256;                                // 65,536
  float* pmax   = dec + 5537792;                                // 800,000 (250x3200)
  float* psum   = dec + 6337792;                                // 800,000
  unsigned short* W1R = (unsigned short*)(dec + 7137792);       // 163,840 f32 slots
  unsigned int* hbuf  = (unsigned int*)(dec + 7301632);         // 8,192
  unsigned int* hflag = (unsigned int*)(dec + 7309824);         // 64 (ends 7,309,888)

  // ws: lse + h_all(bf16) + out_w(bf16)
  float* wsf = (float*)d_ws;
  float* lse = wsf;
  __hip_bfloat16* h_all = (__hip_bfloat16*)(wsf + 3200);
  __hip_bfloat16* w_bf  = h_all + (size_t)Tn*Bn*Hn;

  // prep
  k_tr     <<<dim3(8, 8),   dim3(256), 0, stream>>>(Kw, KwT, 256, 256);
  k_tr     <<<dim3(16, 24), dim3(256), 0, stream>>>(W_ih, W_ihT, 768, 512);
  k_packW1R<<<dim3(160),    dim3(256), 0, stream>>>(Qw, W_hh, W1R);
  k_cvt    <<<dim3((Vn*Hn)/1024), dim3(256), 0, stream>>>(out_w, w_bf, Vn*Hn);
  k_enc2   <<<dim3(256), dim3(256), 0, stream>>>(enc_outputs, KwT, Kb, enc_kb16);
  k_packEk <<<dim3(512), dim3(256), 0, stream>>>(enc_kb16, ekP);
  k_encW2F <<<dim3(256), dim3(768), 0, stream>>>(enc_outputs, W_ihT, encW2F);
  k_giemb2 <<<dim3(200), dim3(768), 0, stream>>>(target, embedding, W_ihT, b_ih, gi_emb);

  // reset flags (stream-ordered before k_loop10)
  hipMemsetAsync((void*)hflag, 0, 64*sizeof(unsigned int), stream);

  // recurrence: 64 co-resident blocks, one lockstep exchange/step, 5 barriers/step
  k_loop10<<<dim3(64), dim3(512), 0, stream>>>(enc_hidden, ekP, encW2F, W1R,
            Qb, b_hh, Vw, Vb, gi_emb, h_all, atts, hfin, hbuf, hflag);

  // logits + log_softmax (staged GEMM; grid = (m, n) for B-strip L2 reuse)
  k_lg3   <<<dim3(25, 250), dim3(256), 0, stream>>>(
            (const unsigned short*)h_all, (const unsigned short*)w_bf, out_b,
            pmax, psum, (const float*)nullptr, (float*)nullptr, 0);
  k_lse2  <<<dim3(50), dim3(256), 0, stream>>>(pmax, psum, lse);
  k_lg3   <<<dim3(25, 250), dim3(256), 0, stream>>>(
            (const unsigned short*)h_all, (const unsigned short*)w_bf, out_b,
            (float*)nullptr, (float*)nullptr, lse, dec, 1);
}